// Round 1
// baseline (1480.121 us; speedup 1.0000x reference)
//
#include <hip/hip_runtime.h>

// Problem constants (reference: N=100000, E=1600000, D=128, H1=512, H2=256).
// N is divisible by 32 (3125 blocks of 32 rows) and by 8; E divisible by 256.
#define DN  128
#define H1N 512
#define H2N 256

// ---------------- preprocessing: degree, dinv, scan, CSR fill ----------------

__global__ __launch_bounds__(256) void k_deg(const int* __restrict__ dst,
                                             int* __restrict__ deg, int E) {
  int e = blockIdx.x * 256 + threadIdx.x;
  if (e < E) atomicAdd(&deg[dst[e]], 1);
}

__global__ __launch_bounds__(256) void k_dinv(const int* __restrict__ deg,
                                              float* __restrict__ dinv, int N) {
  int i = blockIdx.x * 256 + threadIdx.x;
  if (i < N) dinv[i] = rsqrtf((float)(deg[i] + 1));  // +1 self-loop
}

__global__ __launch_bounds__(256) void k_scan_a(const int* __restrict__ deg,
                                                int* __restrict__ excl,
                                                int* __restrict__ sums, int N) {
  __shared__ int s[256];
  int t = threadIdx.x;
  int i = blockIdx.x * 256 + t;
  int v = (i < N) ? deg[i] : 0;
  s[t] = v; __syncthreads();
  for (int o = 1; o < 256; o <<= 1) {
    int a = (t >= o) ? s[t - o] : 0;
    __syncthreads();
    s[t] += a;
    __syncthreads();
  }
  if (i < N) excl[i] = s[t] - v;
  if (t == 255) sums[blockIdx.x] = s[255];
}

__global__ __launch_bounds__(512) void k_scan_b(int* __restrict__ sums, int nb) {
  __shared__ int s[512];
  int t = threadIdx.x;
  int v = (t < nb) ? sums[t] : 0;
  s[t] = v; __syncthreads();
  for (int o = 1; o < 512; o <<= 1) {
    int a = (t >= o) ? s[t - o] : 0;
    __syncthreads();
    s[t] += a;
    __syncthreads();
  }
  if (t < nb) sums[t] = s[t] - v;
}

__global__ __launch_bounds__(256) void k_scan_c(int* __restrict__ ro,
                                                const int* __restrict__ sums,
                                                int* __restrict__ cursor,
                                                int N, int E) {
  int i = blockIdx.x * 256 + threadIdx.x;
  if (i < N) {
    int v = ro[i] + sums[blockIdx.x];
    ro[i] = v;
    cursor[i] = v;
  }
  if (i == 0) ro[N] = E;
}

__global__ __launch_bounds__(256) void k_csr(const int* __restrict__ ei,
                                             int* __restrict__ cursor,
                                             int* __restrict__ csr, int E) {
  int e = blockIdx.x * 256 + threadIdx.x;
  if (e < E) {
    int s = ei[e];            // src row
    int d = ei[E + e];        // dst row
    int pos = atomicAdd(&cursor[d], 1);
    csr[pos] = s;
  }
}

// ---------------- GEMM1: h = x @ W_gcn  (N x 128 @ 128 x 128) ----------------

__global__ __launch_bounds__(256) void k_gemm1(const float* __restrict__ x,
                                               const float* __restrict__ Wg,
                                               float* __restrict__ h, int N) {
  __shared__ float xl[32][DN];  // 16 KB
  int t = threadIdx.x;
  int row0 = blockIdx.x * 32;
  const float4* src = (const float4*)(x + (size_t)row0 * DN);
  float4* dv = (float4*)&xl[0][0];
#pragma unroll
  for (int i = 0; i < 4; i++) dv[t + 256 * i] = src[t + 256 * i];
  __syncthreads();

  int c = t & 127, rh = t >> 7;  // col, row-half
  float acc[16];
#pragma unroll
  for (int r = 0; r < 16; r++) acc[r] = 0.f;

  for (int k = 0; k < DN; k += 4) {
    float w0 = Wg[(k + 0) * DN + c];
    float w1 = Wg[(k + 1) * DN + c];
    float w2 = Wg[(k + 2) * DN + c];
    float w3 = Wg[(k + 3) * DN + c];
#pragma unroll
    for (int r = 0; r < 16; r++) {
      float4 a = *(const float4*)&xl[rh * 16 + r][k];
      acc[r] += a.x * w0 + a.y * w1 + a.z * w2 + a.w * w3;
    }
  }
#pragma unroll
  for (int r = 0; r < 16; r++)
    h[(size_t)(row0 + rh * 16 + r) * DN + c] = acc[r];
}

// --------- aggregation: agg = relu(scatter(norm*h) + self + b) + x -----------
// 8 nodes per 256-thread block; 32 lanes per node, 4 dims (float4) per lane.

__global__ __launch_bounds__(256) void k_agg(const float* __restrict__ h,
                                             const float* __restrict__ x,
                                             const int* __restrict__ csr,
                                             const int* __restrict__ ro,
                                             const float* __restrict__ dinv,
                                             const float* __restrict__ bg,
                                             float* __restrict__ agg, int N) {
  int t = threadIdx.x;
  int node = blockIdx.x * 8 + (t >> 5);
  if (node >= N) return;
  int d4 = (t & 31) * 4;

  int beg = ro[node], end = ro[node + 1];
  float ax = 0.f, ay = 0.f, az = 0.f, aw = 0.f;
  for (int e = beg; e < end; ++e) {
    int s = csr[e];
    float ds = dinv[s];
    float4 hv = *(const float4*)&h[(size_t)s * DN + d4];
    ax += hv.x * ds; ay += hv.y * ds; az += hv.z * ds; aw += hv.w * ds;
  }
  float di = dinv[node];
  float4 hs = *(const float4*)&h[(size_t)node * DN + d4];
  float4 bb = *(const float4*)&bg[d4];
  float4 xv = *(const float4*)&x[(size_t)node * DN + d4];
  float4 o;
  o.x = fmaxf(ax * di + hs.x * di * di + bb.x, 0.f) + xv.x;
  o.y = fmaxf(ay * di + hs.y * di * di + bb.y, 0.f) + xv.y;
  o.z = fmaxf(az * di + hs.z * di * di + bb.z, 0.f) + xv.z;
  o.w = fmaxf(aw * di + hs.w * di * di + bb.w, 0.f) + xv.w;
  *(float4*)&agg[(size_t)node * DN + d4] = o;
}

// ---------------- fused MLP: out = relu(relu(a@W1+b1)@W2+b2)@W3+b3 ----------
// 32 rows per block; t1 (32x512) and t2 (32x256) staged in LDS.

__global__ __launch_bounds__(256) void k_mlp(const float* __restrict__ agg,
                                             const float* __restrict__ W1,
                                             const float* __restrict__ b1,
                                             const float* __restrict__ W2,
                                             const float* __restrict__ b2,
                                             const float* __restrict__ W3,
                                             const float* __restrict__ b3,
                                             float* __restrict__ out, int N) {
  __shared__ float a_lds[32][DN];   // 16 KB
  __shared__ float t1[32][H1N];     // 64 KB
  __shared__ float t2[32][H2N];     // 32 KB

  int t = threadIdx.x;
  int row0 = blockIdx.x * 32;

  // load 32 input rows
  {
    const float4* src = (const float4*)(agg + (size_t)row0 * DN);
    float4* dv = (float4*)&a_lds[0][0];
#pragma unroll
    for (int i = 0; i < 4; i++) dv[t + 256 * i] = src[t + 256 * i];
  }
  __syncthreads();

  // ---- stage 1: t1 = relu(a @ W1 + b1), K=128, cols c0=t, c1=t+256 ----
  {
    float acc0[32], acc1[32];
#pragma unroll
    for (int r = 0; r < 32; r++) { acc0[r] = 0.f; acc1[r] = 0.f; }
    int c0 = t, c1 = t + 256;
    for (int k = 0; k < DN; k += 4) {
      float w00 = W1[(k + 0) * H1N + c0];
      float w01 = W1[(k + 1) * H1N + c0];
      float w02 = W1[(k + 2) * H1N + c0];
      float w03 = W1[(k + 3) * H1N + c0];
      float w10 = W1[(k + 0) * H1N + c1];
      float w11 = W1[(k + 1) * H1N + c1];
      float w12 = W1[(k + 2) * H1N + c1];
      float w13 = W1[(k + 3) * H1N + c1];
#pragma unroll
      for (int r = 0; r < 32; r++) {
        float4 a = *(const float4*)&a_lds[r][k];
        acc0[r] += a.x * w00 + a.y * w01 + a.z * w02 + a.w * w03;
        acc1[r] += a.x * w10 + a.y * w11 + a.z * w12 + a.w * w13;
      }
    }
    float bb0 = b1[c0], bb1 = b1[c1];
#pragma unroll
    for (int r = 0; r < 32; r++) {
      t1[r][c0] = fmaxf(acc0[r] + bb0, 0.f);
      t1[r][c1] = fmaxf(acc1[r] + bb1, 0.f);
    }
  }
  __syncthreads();

  // ---- stage 2: t2 = relu(t1 @ W2 + b2), K=512 ----
  {
    int c = t & 127, rh = t >> 7;  // 2 cols (c, c+128), 16 rows per thread
    float acc0[16], acc1[16];
#pragma unroll
    for (int r = 0; r < 16; r++) { acc0[r] = 0.f; acc1[r] = 0.f; }
    for (int k = 0; k < H1N; k += 4) {
      float w00 = W2[(k + 0) * H2N + c];
      float w01 = W2[(k + 1) * H2N + c];
      float w02 = W2[(k + 2) * H2N + c];
      float w03 = W2[(k + 3) * H2N + c];
      float w10 = W2[(k + 0) * H2N + c + 128];
      float w11 = W2[(k + 1) * H2N + c + 128];
      float w12 = W2[(k + 2) * H2N + c + 128];
      float w13 = W2[(k + 3) * H2N + c + 128];
#pragma unroll
      for (int r = 0; r < 16; r++) {
        float4 a = *(const float4*)&t1[rh * 16 + r][k];
        acc0[r] += a.x * w00 + a.y * w01 + a.z * w02 + a.w * w03;
        acc1[r] += a.x * w10 + a.y * w11 + a.z * w12 + a.w * w13;
      }
    }
    float bb0 = b2[c], bb1 = b2[c + 128];
#pragma unroll
    for (int r = 0; r < 16; r++) {
      t2[rh * 16 + r][c]       = fmaxf(acc0[r] + bb0, 0.f);
      t2[rh * 16 + r][c + 128] = fmaxf(acc1[r] + bb1, 0.f);
    }
  }
  __syncthreads();

  // ---- stage 3: out = t2 @ W3 + b3, K=256; 8 lanes per row ----
  {
    int r = t >> 3, p = t & 7;
    float sum = 0.f;
#pragma unroll
    for (int i = 0; i < 8; i++) {
      float4 a = *(const float4*)&t2[r][p * 32 + i * 4];
      float4 w = *(const float4*)&W3[p * 32 + i * 4];
      sum += a.x * w.x + a.y * w.y + a.z * w.z + a.w * w.w;
    }
    sum += __shfl_down(sum, 4, 8);
    sum += __shfl_down(sum, 2, 8);
    sum += __shfl_down(sum, 1, 8);
    if (p == 0) out[row0 + r] = sum + b3[0];
  }
}

// ------------------------------- launcher ------------------------------------

extern "C" void kernel_launch(void* const* d_in, const int* in_sizes, int n_in,
                              void* d_out, int out_size, void* d_ws, size_t ws_size,
                              hipStream_t stream) {
  const float* x  = (const float*)d_in[0];
  const int*   ei = (const int*)d_in[1];   // [2, E] flattened: [0..E)=src, [E..2E)=dst
  const float* Wg = (const float*)d_in[2];
  const float* bg = (const float*)d_in[3];
  const float* W1 = (const float*)d_in[4];
  const float* b1 = (const float*)d_in[5];
  const float* W2 = (const float*)d_in[6];
  const float* b2 = (const float*)d_in[7];
  const float* W3 = (const float*)d_in[8];
  const float* b3 = (const float*)d_in[9];
  float* out = (float*)d_out;

  const int N = in_sizes[0] / DN;
  const int E = in_sizes[1] / 2;

  char* ws = (char*)d_ws;
  size_t off = 0;
  auto alloc = [&](size_t bytes) -> void* {
    void* p = ws + off;
    off = (off + bytes + 255) & ~(size_t)255;
    return p;
  };
  int*   deg    = (int*)alloc((size_t)N * 4);
  int*   ro     = (int*)alloc(((size_t)N + 1) * 4);
  int*   cursor = (int*)alloc((size_t)N * 4);
  int*   sums   = (int*)alloc(4096);
  float* dinv   = (float*)alloc((size_t)N * 4);
  int*   csr    = (int*)alloc((size_t)E * 4);
  float* h      = (float*)alloc((size_t)N * DN * 4);
  float* agg    = (float*)alloc((size_t)N * DN * 4);
  (void)ws_size; (void)n_in; (void)out_size;

  hipMemsetAsync(deg, 0, (size_t)N * 4, stream);

  k_deg<<<(E + 255) / 256, 256, 0, stream>>>(ei + E, deg, E);
  k_dinv<<<(N + 255) / 256, 256, 0, stream>>>(deg, dinv, N);

  int nb = (N + 255) / 256;
  k_scan_a<<<nb, 256, 0, stream>>>(deg, ro, sums, N);
  k_scan_b<<<1, 512, 0, stream>>>(sums, nb);
  k_scan_c<<<nb, 256, 0, stream>>>(ro, sums, cursor, N, E);
  k_csr<<<(E + 255) / 256, 256, 0, stream>>>(ei, cursor, csr, E);

  k_gemm1<<<N / 32, 256, 0, stream>>>(x, Wg, h, N);
  k_agg<<<N / 8, 256, 0, stream>>>(h, x, csr, ro, dinv, bg, agg, N);
  k_mlp<<<N / 32, 256, 0, stream>>>(agg, W1, b1, W2, b2, W3, b3, out, N);
}

// Round 2
// 553.281 us; speedup vs baseline: 2.6752x; 2.6752x over previous
//
#include <hip/hip_runtime.h>

#define DN  128
#define H1N 512
#define H2N 256

typedef __attribute__((ext_vector_type(8))) short short8_t;   // 8 bf16
typedef __attribute__((ext_vector_type(4))) float f32x4;      // MFMA acc

__device__ inline ushort f2bf(float f) {
  union { float f; unsigned u; } v; v.f = f;
  unsigned r = v.u + 0x7FFF + ((v.u >> 16) & 1);   // RNE
  return (ushort)(r >> 16);
}
__device__ inline float bf2f(ushort u) {
  union { unsigned u; float f; } v; v.u = ((unsigned)u) << 16;
  return v.f;
}

// ---------------- preprocessing: degree, dinv, scan, CSR fill ----------------

__global__ __launch_bounds__(256) void k_deg(const int* __restrict__ dst,
                                             int* __restrict__ deg, int E) {
  int e = blockIdx.x * 256 + threadIdx.x;
  if (e < E) atomicAdd(&deg[dst[e]], 1);
}

__global__ __launch_bounds__(256) void k_dinv(const int* __restrict__ deg,
                                              float* __restrict__ dinv, int N) {
  int i = blockIdx.x * 256 + threadIdx.x;
  if (i < N) dinv[i] = rsqrtf((float)(deg[i] + 1));  // +1 self-loop
}

__global__ __launch_bounds__(256) void k_scan_a(const int* __restrict__ deg,
                                                int* __restrict__ excl,
                                                int* __restrict__ sums, int N) {
  __shared__ int s[256];
  int t = threadIdx.x;
  int i = blockIdx.x * 256 + t;
  int v = (i < N) ? deg[i] : 0;
  s[t] = v; __syncthreads();
  for (int o = 1; o < 256; o <<= 1) {
    int a = (t >= o) ? s[t - o] : 0;
    __syncthreads();
    s[t] += a;
    __syncthreads();
  }
  if (i < N) excl[i] = s[t] - v;
  if (t == 255) sums[blockIdx.x] = s[255];
}

__global__ __launch_bounds__(512) void k_scan_b(int* __restrict__ sums, int nb) {
  __shared__ int s[512];
  int t = threadIdx.x;
  int v = (t < nb) ? sums[t] : 0;
  s[t] = v; __syncthreads();
  for (int o = 1; o < 512; o <<= 1) {
    int a = (t >= o) ? s[t - o] : 0;
    __syncthreads();
    s[t] += a;
    __syncthreads();
  }
  if (t < nb) sums[t] = s[t] - v;
}

__global__ __launch_bounds__(256) void k_scan_c(int* __restrict__ ro,
                                                const int* __restrict__ sums,
                                                int* __restrict__ cursor,
                                                int N, int E) {
  int i = blockIdx.x * 256 + threadIdx.x;
  if (i < N) {
    int v = ro[i] + sums[blockIdx.x];
    ro[i] = v;
    cursor[i] = v;
  }
  if (i == 0) ro[N] = E;
}

__global__ __launch_bounds__(256) void k_csr(const int* __restrict__ ei,
                                             int* __restrict__ cursor,
                                             int* __restrict__ csr, int E) {
  int e = blockIdx.x * 256 + threadIdx.x;
  if (e < E) {
    int s = ei[e];
    int d = ei[E + e];
    int pos = atomicAdd(&cursor[d], 1);
    csr[pos] = s;
  }
}

// ------------- weight repack into MFMA B-fragment order (bf16) ---------------
// Wp[ct][ks][lane][8] = W[ks*32 + (lane>>4)*8 + r][ct*16 + (lane&15)]

__global__ __launch_bounds__(256) void k_pack(const float* __restrict__ W,
                                              ushort* __restrict__ Wp,
                                              int K, int Ncols) {
  int idx = blockIdx.x * 256 + threadIdx.x;
  int ksn = K >> 5;
  int total = (Ncols >> 4) * ksn * 64;
  if (idx >= total) return;
  int l  = idx & 63;
  int ks = (idx >> 6) % ksn;
  int ct = idx / (64 * ksn);
  int col = ct * 16 + (l & 15);
  int kb  = ks * 32 + (l >> 4) * 8;
  short8_t v;
#pragma unroll
  for (int r = 0; r < 8; ++r)
    v[r] = (short)f2bf(W[(size_t)(kb + r) * Ncols + col]);
  *(short8_t*)&Wp[(size_t)idx * 8] = v;
}

// ---------------- GEMM1: hs = (x @ W_gcn) * dinv[row]  (bf16 out) ------------

__global__ __launch_bounds__(256, 2) void k_gemm1(const float* __restrict__ x,
                                                  const ushort* __restrict__ Wgp,
                                                  const float* __restrict__ dinv,
                                                  ushort* __restrict__ hs, int N) {
  __shared__ ushort xT[64 * 128];  // bf16, XOR-swizzled, 16 KB
  int t = threadIdx.x;
  int row0 = blockIdx.x * 64;

#pragma unroll
  for (int i = 0; i < 4; ++i) {
    int c = t + 256 * i;          // 1024 chunks of 8 dims
    int r = c >> 4, d0 = (c & 15) * 8;
    int gr = row0 + r;
    float4 v0 = {0,0,0,0}, v1 = {0,0,0,0};
    if (gr < N) {
      v0 = *(const float4*)(x + (size_t)gr * DN + d0);
      v1 = *(const float4*)(x + (size_t)gr * DN + d0 + 4);
    }
    short8_t p;
    p[0]=(short)f2bf(v0.x); p[1]=(short)f2bf(v0.y); p[2]=(short)f2bf(v0.z); p[3]=(short)f2bf(v0.w);
    p[4]=(short)f2bf(v1.x); p[5]=(short)f2bf(v1.y); p[6]=(short)f2bf(v1.z); p[7]=(short)f2bf(v1.w);
    *(short8_t*)((char*)xT + r * 256 + ((d0 * 2) ^ ((r & 7) << 4))) = p;
  }
  __syncthreads();

  int w = t >> 6, l = t & 63;
  int lr = l & 15, lk = l >> 4;
  int rw = w * 16;

  short8_t a1[4];
#pragma unroll
  for (int ks = 0; ks < 4; ++ks) {
    int r = rw + lr;
    int cb = ks * 64 + lk * 16;
    a1[ks] = *(const short8_t*)((const char*)xT + r * 256 + (cb ^ ((r & 7) << 4)));
  }

  f32x4 acc[8];
#pragma unroll
  for (int ct = 0; ct < 8; ++ct) acc[ct] = (f32x4){0.f,0.f,0.f,0.f};
  const short8_t* pb = (const short8_t*)Wgp;
#pragma unroll
  for (int ks = 0; ks < 4; ++ks)
#pragma unroll
    for (int ct = 0; ct < 8; ++ct) {
      short8_t b = pb[(ct * 4 + ks) * 64 + l];
      acc[ct] = __builtin_amdgcn_mfma_f32_16x16x32_bf16(a1[ks], b, acc[ct], 0, 0, 0);
    }

#pragma unroll
  for (int r2 = 0; r2 < 4; ++r2) {
    int gr = row0 + rw + lk * 4 + r2;
    if (gr < N) {
      float dv = dinv[gr];
#pragma unroll
      for (int ct = 0; ct < 8; ++ct)
        hs[(size_t)gr * DN + ct * 16 + lr] = f2bf(acc[ct][r2] * dv);
    }
  }
}

// --------- aggregation: agg = bf16(relu(dinv*(sum+self) + b) + x) ------------

__global__ __launch_bounds__(256) void k_agg(const ushort* __restrict__ hs,
                                             const float* __restrict__ x,
                                             const int* __restrict__ csr,
                                             const int* __restrict__ ro,
                                             const float* __restrict__ dinv,
                                             const float* __restrict__ bg,
                                             ushort* __restrict__ aggb, int N) {
  int t = threadIdx.x;
  int node = blockIdx.x * 8 + (t >> 5);
  if (node >= N) return;
  int d0 = (t & 31) * 4;

  int beg = ro[node], end = ro[node + 1];
  float s0 = 0.f, s1 = 0.f, s2 = 0.f, s3 = 0.f;
  for (int e = beg; e < end; ++e) {
    int src = csr[e];
    ushort4 hv = *(const ushort4*)(hs + (size_t)src * DN + d0);
    s0 += bf2f(hv.x); s1 += bf2f(hv.y); s2 += bf2f(hv.z); s3 += bf2f(hv.w);
  }
  ushort4 hv = *(const ushort4*)(hs + (size_t)node * DN + d0);
  s0 += bf2f(hv.x); s1 += bf2f(hv.y); s2 += bf2f(hv.z); s3 += bf2f(hv.w);

  float dn = dinv[node];
  float4 xv = *(const float4*)(x + (size_t)node * DN + d0);
  float4 bb = *(const float4*)(bg + d0);
  ushort4 o;
  o.x = f2bf(fmaxf(s0 * dn + bb.x, 0.f) + xv.x);
  o.y = f2bf(fmaxf(s1 * dn + bb.y, 0.f) + xv.y);
  o.z = f2bf(fmaxf(s2 * dn + bb.z, 0.f) + xv.z);
  o.w = f2bf(fmaxf(s3 * dn + bb.w, 0.f) + xv.w);
  *(ushort4*)(aggb + (size_t)node * DN + d0) = o;
}

// ------------- fused MFMA MLP: out = relu(relu(a@W1+b1)@W2+b2)@W3+b3 ---------
// 64 rows/block, 4 waves (16 rows each). agg + t1 in XOR-swizzled LDS (80 KB).
// Stage 3 folded into stage-2 epilogue (shuffle reduction), no t2 buffer.

__global__ __launch_bounds__(256, 2) void k_mlp(const ushort* __restrict__ aggb,
                                                const ushort* __restrict__ W1p,
                                                const float* __restrict__ b1,
                                                const ushort* __restrict__ W2p,
                                                const float* __restrict__ b2,
                                                const float* __restrict__ W3,
                                                const float* __restrict__ b3,
                                                float* __restrict__ out, int N) {
  __shared__ ushort aT[64 * 128];   // 16 KB
  __shared__ ushort t1[64 * 512];   // 64 KB
  int t = threadIdx.x;
  int row0 = blockIdx.x * 64;

  // stage agg rows (bf16, swizzled)
#pragma unroll
  for (int i = 0; i < 4; ++i) {
    int c = t + 256 * i;
    int r = c >> 4;
    int cb = (c & 15) * 16;
    int gr = row0 + r;
    uint4 v = {0, 0, 0, 0};
    if (gr < N) v = *(const uint4*)(aggb + (size_t)gr * DN + (c & 15) * 8);
    *(uint4*)((char*)aT + r * 256 + (cb ^ ((r & 7) << 4))) = v;
  }
  __syncthreads();

  int w = t >> 6, l = t & 63;
  int lr = l & 15, lk = l >> 4;
  int rw = w * 16;

  // ---- stage 1: t1 = relu(a @ W1 + b1) ----
  short8_t a1[4];
#pragma unroll
  for (int ks = 0; ks < 4; ++ks) {
    int r = rw + lr;
    int cb = ks * 64 + lk * 16;
    a1[ks] = *(const short8_t*)((const char*)aT + r * 256 + (cb ^ ((r & 7) << 4)));
  }

  f32x4 acc[32];
#pragma unroll
  for (int ct = 0; ct < 32; ++ct) acc[ct] = (f32x4){0.f,0.f,0.f,0.f};
  const short8_t* pb1 = (const short8_t*)W1p;
#pragma unroll
  for (int ks = 0; ks < 4; ++ks)
#pragma unroll
    for (int ct = 0; ct < 32; ++ct) {
      short8_t b = pb1[(ct * 4 + ks) * 64 + l];
      acc[ct] = __builtin_amdgcn_mfma_f32_16x16x32_bf16(a1[ks], b, acc[ct], 0, 0, 0);
    }

#pragma unroll
  for (int ct = 0; ct < 32; ++ct) {
    int col = ct * 16 + lr;
    float bb = b1[col];
#pragma unroll
    for (int r2 = 0; r2 < 4; ++r2) {
      int rr = rw + lk * 4 + r2;
      float v = fmaxf(acc[ct][r2] + bb, 0.f);
      *(ushort*)((char*)t1 + rr * 1024 + ((col * 2) ^ ((rr & 7) << 4))) = f2bf(v);
    }
  }
  // rows are wave-private: no barrier needed (compiler orders LDS ops)

  // ---- stage 2: c2 = t1 @ W2, K=512 ----
  short8_t a2[16];
#pragma unroll
  for (int ks = 0; ks < 16; ++ks) {
    int r = rw + lr;
    int cb = ks * 64 + lk * 16;
    a2[ks] = *(const short8_t*)((const char*)t1 + r * 1024 + (cb ^ ((r & 7) << 4)));
  }

  f32x4 c2[16];
#pragma unroll
  for (int ct = 0; ct < 16; ++ct) c2[ct] = (f32x4){0.f,0.f,0.f,0.f};
  const short8_t* pb2 = (const short8_t*)W2p;
#pragma unroll
  for (int ks = 0; ks < 16; ++ks)
#pragma unroll
    for (int ct = 0; ct < 16; ++ct) {
      short8_t b = pb2[(ct * 16 + ks) * 64 + l];
      c2[ct] = __builtin_amdgcn_mfma_f32_16x16x32_bf16(a2[ks], b, c2[ct], 0, 0, 0);
    }

  // ---- stage 3 folded: out = relu(c2 + b2) @ W3 + b3 ----
  float po[4] = {0.f, 0.f, 0.f, 0.f};
#pragma unroll
  for (int ct = 0; ct < 16; ++ct) {
    int col = ct * 16 + lr;
    float bb = b2[col];
    float w3 = W3[col];
#pragma unroll
    for (int r2 = 0; r2 < 4; ++r2)
      po[r2] += fmaxf(c2[ct][r2] + bb, 0.f) * w3;
  }
#pragma unroll
  for (int r2 = 0; r2 < 4; ++r2) {
    float v = po[r2];
    v += __shfl_xor(v, 1, 64);
    v += __shfl_xor(v, 2, 64);
    v += __shfl_xor(v, 4, 64);
    v += __shfl_xor(v, 8, 64);
    po[r2] = v;
  }
  if (lr == 0) {
#pragma unroll
    for (int r2 = 0; r2 < 4; ++r2) {
      int gr = row0 + rw + lk * 4 + r2;
      if (gr < N) out[gr] = po[r2] + b3[0];
    }
  }
}

// ------------------------------- launcher ------------------------------------

extern "C" void kernel_launch(void* const* d_in, const int* in_sizes, int n_in,
                              void* d_out, int out_size, void* d_ws, size_t ws_size,
                              hipStream_t stream) {
  const float* x  = (const float*)d_in[0];
  const int*   ei = (const int*)d_in[1];
  const float* Wg = (const float*)d_in[2];
  const float* bg = (const float*)d_in[3];
  const float* W1 = (const float*)d_in[4];
  const float* b1 = (const float*)d_in[5];
  const float* W2 = (const float*)d_in[6];
  const float* b2 = (const float*)d_in[7];
  const float* W3 = (const float*)d_in[8];
  const float* b3 = (const float*)d_in[9];
  float* out = (float*)d_out;

  const int N = in_sizes[0] / DN;
  const int E = in_sizes[1] / 2;

  char* ws = (char*)d_ws;
  size_t off = 0;
  auto alloc = [&](size_t bytes) -> void* {
    void* p = ws + off;
    off = (off + bytes + 255) & ~(size_t)255;
    return p;
  };
  int*    deg    = (int*)alloc((size_t)N * 4);
  int*    ro     = (int*)alloc(((size_t)N + 1) * 4);
  int*    cursor = (int*)alloc((size_t)N * 4);
  int*    sums   = (int*)alloc(4096);
  float*  dinv   = (float*)alloc((size_t)N * 4);
  int*    csr    = (int*)alloc((size_t)E * 4);
  ushort* hsb    = (ushort*)alloc((size_t)N * DN * 2);
  ushort* aggb   = (ushort*)alloc((size_t)N * DN * 2);
  ushort* Wgp    = (ushort*)alloc((size_t)DN * DN * 2);
  ushort* W1p    = (ushort*)alloc((size_t)DN * H1N * 2);
  ushort* W2p    = (ushort*)alloc((size_t)H1N * H2N * 2);
  (void)ws_size; (void)n_in; (void)out_size;

  hipMemsetAsync(deg, 0, (size_t)N * 4, stream);

  k_deg<<<(E + 255) / 256, 256, 0, stream>>>(ei + E, deg, E);
  k_dinv<<<(N + 255) / 256, 256, 0, stream>>>(deg, dinv, N);

  int nb = (N + 255) / 256;
  k_scan_a<<<nb, 256, 0, stream>>>(deg, ro, sums, N);
  k_scan_b<<<1, 512, 0, stream>>>(sums, nb);
  k_scan_c<<<nb, 256, 0, stream>>>(ro, sums, cursor, N, E);
  k_csr<<<(E + 255) / 256, 256, 0, stream>>>(ei, cursor, csr, E);

  // weight repacks (bf16 fragment layout)
  k_pack<<<(DN / 32 * DN / 16 * 64 + 255) / 256, 256, 0, stream>>>(Wg, Wgp, DN, DN);
  k_pack<<<(DN / 32 * H1N / 16 * 64 + 255) / 256, 256, 0, stream>>>(W1, W1p, DN, H1N);
  k_pack<<<(H1N / 32 * H2N / 16 * 64 + 255) / 256, 256, 0, stream>>>(W2, W2p, H1N, H2N);

  int nb64 = (N + 63) / 64;
  k_gemm1<<<nb64, 256, 0, stream>>>(x, Wgp, dinv, hsb, N);
  k_agg<<<(N + 7) / 8, 256, 0, stream>>>(hsb, x, csr, ro, dinv, bg, aggb, N);
  k_mlp<<<nb64, 256, 0, stream>>>(aggb, W1p, b1, W2p, b2, W3, b3, out, N);
}

// Round 3
// 362.339 us; speedup vs baseline: 4.0849x; 1.5270x over previous
//
#include <hip/hip_runtime.h>

#define DN  128
#define H1N 512
#define H2N 256

typedef __attribute__((ext_vector_type(8))) short short8_t;   // 8 bf16
typedef __attribute__((ext_vector_type(4))) float f32x4;      // MFMA acc

__device__ inline ushort f2bf(float f) {
  union { float f; unsigned u; } v; v.f = f;
  unsigned r = v.u + 0x7FFF + ((v.u >> 16) & 1);   // RNE
  return (ushort)(r >> 16);
}
__device__ inline float bf2f(ushort u) {
  union { unsigned u; float f; } v; v.u = ((unsigned)u) << 16;
  return v.f;
}

// ---------------- preprocessing: degree, dinv, scan, CSR fill ----------------

__global__ __launch_bounds__(256) void k_deg(const int* __restrict__ dst,
                                             int* __restrict__ deg, int E) {
  int e = blockIdx.x * 256 + threadIdx.x;
  if (e < E) atomicAdd(&deg[dst[e]], 1);
}

__global__ __launch_bounds__(256) void k_dinv(const int* __restrict__ deg,
                                              float* __restrict__ dinv, int N) {
  int i = blockIdx.x * 256 + threadIdx.x;
  if (i < N) dinv[i] = rsqrtf((float)(deg[i] + 1));  // +1 self-loop
}

__global__ __launch_bounds__(256) void k_scan_a(const int* __restrict__ deg,
                                                int* __restrict__ excl,
                                                int* __restrict__ sums, int N) {
  __shared__ int s[256];
  int t = threadIdx.x;
  int i = blockIdx.x * 256 + t;
  int v = (i < N) ? deg[i] : 0;
  s[t] = v; __syncthreads();
  for (int o = 1; o < 256; o <<= 1) {
    int a = (t >= o) ? s[t - o] : 0;
    __syncthreads();
    s[t] += a;
    __syncthreads();
  }
  if (i < N) excl[i] = s[t] - v;
  if (t == 255) sums[blockIdx.x] = s[255];
}

__global__ __launch_bounds__(512) void k_scan_b(int* __restrict__ sums, int nb) {
  __shared__ int s[512];
  int t = threadIdx.x;
  int v = (t < nb) ? sums[t] : 0;
  s[t] = v; __syncthreads();
  for (int o = 1; o < 512; o <<= 1) {
    int a = (t >= o) ? s[t - o] : 0;
    __syncthreads();
    s[t] += a;
    __syncthreads();
  }
  if (t < nb) sums[t] = s[t] - v;
}

__global__ __launch_bounds__(256) void k_scan_c(int* __restrict__ ro,
                                                const int* __restrict__ sums,
                                                int* __restrict__ cursor,
                                                int N, int E) {
  int i = blockIdx.x * 256 + threadIdx.x;
  if (i < N) {
    int v = ro[i] + sums[blockIdx.x];
    ro[i] = v;
    cursor[i] = v;
  }
  if (i == 0) ro[N] = E;
}

__global__ __launch_bounds__(256) void k_csr(const int* __restrict__ ei,
                                             int* __restrict__ cursor,
                                             int* __restrict__ csr, int E) {
  int e = blockIdx.x * 256 + threadIdx.x;
  if (e < E) {
    int s = ei[e];
    int d = ei[E + e];
    int pos = atomicAdd(&cursor[d], 1);
    csr[pos] = s;
  }
}

// ------------- weight repack into MFMA B-fragment order (bf16) ---------------
// Wp[ct][ks][lane][8] = W[ks*32 + (lane>>4)*8 + r][ct*16 + (lane&15)]

__global__ __launch_bounds__(256) void k_pack(const float* __restrict__ W,
                                              ushort* __restrict__ Wp,
                                              int K, int Ncols) {
  int idx = blockIdx.x * 256 + threadIdx.x;
  int ksn = K >> 5;
  int total = (Ncols >> 4) * ksn * 64;
  if (idx >= total) return;
  int l  = idx & 63;
  int ks = (idx >> 6) % ksn;
  int ct = idx / (64 * ksn);
  int col = ct * 16 + (l & 15);
  int kb  = ks * 32 + (l >> 4) * 8;
  short8_t v;
#pragma unroll
  for (int r = 0; r < 8; ++r)
    v[r] = (short)f2bf(W[(size_t)(kb + r) * Ncols + col]);
  *(short8_t*)&Wp[(size_t)idx * 8] = v;
}

// ---------------- GEMM1: hs = (x @ W_gcn) * dinv[row]  (bf16 out) ------------
// 64 rows/block; waves col-split: wave w owns cols [w*32,(w+1)*32), M_rep=4.

__global__ __launch_bounds__(256, 4) void k_gemm1(const float* __restrict__ x,
                                                  const ushort* __restrict__ Wgp,
                                                  const float* __restrict__ dinv,
                                                  ushort* __restrict__ hs, int N) {
  __shared__ ushort xT[64 * 128];  // bf16, XOR-swizzled, 16 KB
  int t = threadIdx.x;
  int row0 = blockIdx.x * 64;

#pragma unroll
  for (int i = 0; i < 4; ++i) {
    int c = t + 256 * i;          // 1024 chunks of 8 dims
    int r = c >> 4, d0 = (c & 15) * 8;
    int gr = row0 + r;
    float4 v0 = {0,0,0,0}, v1 = {0,0,0,0};
    if (gr < N) {
      v0 = *(const float4*)(x + (size_t)gr * DN + d0);
      v1 = *(const float4*)(x + (size_t)gr * DN + d0 + 4);
    }
    short8_t p;
    p[0]=(short)f2bf(v0.x); p[1]=(short)f2bf(v0.y); p[2]=(short)f2bf(v0.z); p[3]=(short)f2bf(v0.w);
    p[4]=(short)f2bf(v1.x); p[5]=(short)f2bf(v1.y); p[6]=(short)f2bf(v1.z); p[7]=(short)f2bf(v1.w);
    *(short8_t*)((char*)xT + r * 256 + ((d0 * 2) ^ ((r & 7) << 4))) = p;
  }
  __syncthreads();

  int w = t >> 6, l = t & 63;
  int lr = l & 15, lk = l >> 4;
  const short8_t* pbg = (const short8_t*)Wgp;

  f32x4 acc[4][2];
#pragma unroll
  for (int mf = 0; mf < 4; ++mf)
#pragma unroll
    for (int n = 0; n < 2; ++n) acc[mf][n] = (f32x4){0.f,0.f,0.f,0.f};

  auto g_load = [&](short8_t (&bb)[2], int ks) {
#pragma unroll
    for (int n = 0; n < 2; ++n)
      bb[n] = pbg[((w * 2 + n) * 4 + ks) * 64 + l];
  };
  auto g_mfma = [&](short8_t (&bb)[2], int ks) {
    short8_t a[4];
#pragma unroll
    for (int mf = 0; mf < 4; ++mf) {
      int r = mf * 16 + lr;
      a[mf] = *(const short8_t*)((const char*)xT + r * 256 + ((ks * 64 + lk * 16) ^ ((r & 7) << 4)));
    }
#pragma unroll
    for (int mf = 0; mf < 4; ++mf)
#pragma unroll
      for (int n = 0; n < 2; ++n)
        acc[mf][n] = __builtin_amdgcn_mfma_f32_16x16x32_bf16(a[mf], bb[n], acc[mf][n], 0, 0, 0);
  };

  short8_t bA[2], bB[2];
  g_load(bA, 0);
  g_load(bB, 1); g_mfma(bA, 0);
  g_load(bA, 2); g_mfma(bB, 1);
  g_load(bB, 3); g_mfma(bA, 2);
  g_mfma(bB, 3);

  float dv[4][4];
#pragma unroll
  for (int mf = 0; mf < 4; ++mf)
#pragma unroll
    for (int r2 = 0; r2 < 4; ++r2) {
      int gr = row0 + mf * 16 + lk * 4 + r2;
      dv[mf][r2] = (gr < N) ? dinv[gr] : 0.f;
    }
#pragma unroll
  for (int n = 0; n < 2; ++n) {
    int col = (w * 2 + n) * 16 + lr;
#pragma unroll
    for (int mf = 0; mf < 4; ++mf)
#pragma unroll
      for (int r2 = 0; r2 < 4; ++r2) {
        int gr = row0 + mf * 16 + lk * 4 + r2;
        if (gr < N) hs[(size_t)gr * DN + col] = f2bf(acc[mf][n][r2] * dv[mf][r2]);
      }
  }
}

// --------- aggregation: agg = bf16(relu(dinv*(sum+self) + b) + x) ------------
// 16 nodes per 256-thread block; 16 lanes/node, 8 dims (uint4) per lane.

__global__ __launch_bounds__(256) void k_agg(const ushort* __restrict__ hs,
                                             const float* __restrict__ x,
                                             const int* __restrict__ csr,
                                             const int* __restrict__ ro,
                                             const float* __restrict__ dinv,
                                             const float* __restrict__ bg,
                                             ushort* __restrict__ aggb, int N) {
  int t = threadIdx.x;
  int node = blockIdx.x * 16 + (t >> 4);
  if (node >= N) return;
  int d0 = (t & 15) * 8;

  float s[8];
#pragma unroll
  for (int i = 0; i < 8; ++i) s[i] = 0.f;

  auto accum = [&](uint4 v) {
    s[0] += bf2f((ushort)(v.x & 0xffff)); s[1] += bf2f((ushort)(v.x >> 16));
    s[2] += bf2f((ushort)(v.y & 0xffff)); s[3] += bf2f((ushort)(v.y >> 16));
    s[4] += bf2f((ushort)(v.z & 0xffff)); s[5] += bf2f((ushort)(v.z >> 16));
    s[6] += bf2f((ushort)(v.w & 0xffff)); s[7] += bf2f((ushort)(v.w >> 16));
  };

  int beg = ro[node], end = ro[node + 1];
  int e = beg;
  for (; e + 2 <= end; e += 2) {
    int s0 = csr[e], s1 = csr[e + 1];
    uint4 v0 = *(const uint4*)(hs + (size_t)s0 * DN + d0);
    uint4 v1 = *(const uint4*)(hs + (size_t)s1 * DN + d0);
    accum(v0); accum(v1);
  }
  if (e < end) {
    int s0 = csr[e];
    accum(*(const uint4*)(hs + (size_t)s0 * DN + d0));
  }
  accum(*(const uint4*)(hs + (size_t)node * DN + d0));  // self (pre-scaled)

  float dn = dinv[node];
  float4 x0 = *(const float4*)(x + (size_t)node * DN + d0);
  float4 x1 = *(const float4*)(x + (size_t)node * DN + d0 + 4);
  float4 b0 = *(const float4*)(bg + d0);
  float4 b1v = *(const float4*)(bg + d0 + 4);
  float xv[8] = {x0.x, x0.y, x0.z, x0.w, x1.x, x1.y, x1.z, x1.w};
  float bv[8] = {b0.x, b0.y, b0.z, b0.w, b1v.x, b1v.y, b1v.z, b1v.w};
  uint out[4];
#pragma unroll
  for (int i = 0; i < 4; ++i) {
    ushort lo = f2bf(fmaxf(s[2*i]   * dn + bv[2*i],   0.f) + xv[2*i]);
    ushort hi = f2bf(fmaxf(s[2*i+1] * dn + bv[2*i+1], 0.f) + xv[2*i+1]);
    out[i] = (uint)lo | ((uint)hi << 16);
  }
  *(uint4*)(aggb + (size_t)node * DN + d0) = *(uint4*)out;
}

// ------------- fused MFMA MLP: out = relu(relu(a@W1+b1)@W2+b2)@W3+b3 ---------
// 64 rows/block, 4 waves. Col-split: wave w owns stage-1 cols [w*128,(w+1)*128)
// and stage-2 cols [w*64,(w+1)*64), M_rep=4 (all 64 rows). Double-buffered B
// prefetch from L2. Stage 3 folded + cross-wave LDS reduction (reuses aT).

__global__ __launch_bounds__(256, 2) void k_mlp(const ushort* __restrict__ aggb,
                                                const ushort* __restrict__ W1p,
                                                const float* __restrict__ b1,
                                                const ushort* __restrict__ W2p,
                                                const float* __restrict__ b2,
                                                const float* __restrict__ W3,
                                                const float* __restrict__ b3,
                                                float* __restrict__ out, int N) {
  __shared__ ushort aT[64 * 128];   // 16 KB (reused as pf[4][64] floats later)
  __shared__ ushort t1[64 * 512];   // 64 KB
  int t = threadIdx.x;
  int row0 = blockIdx.x * 64;

  // stage agg rows (bf16, swizzled)
#pragma unroll
  for (int i = 0; i < 4; ++i) {
    int c = t + 256 * i;
    int r = c >> 4;
    int cb = (c & 15) * 16;
    int gr = row0 + r;
    uint4 v = {0, 0, 0, 0};
    if (gr < N) v = *(const uint4*)(aggb + (size_t)gr * DN + (c & 15) * 8);
    *(uint4*)((char*)aT + r * 256 + (cb ^ ((r & 7) << 4))) = v;
  }
  __syncthreads();

  int w = t >> 6, l = t & 63;
  int lr = l & 15, lk = l >> 4;

  // ---- stage 1: t1[:, w*128:(w+1)*128] = relu(a @ W1 + b1) ----
  const short8_t* pb1 = (const short8_t*)W1p;
  f32x4 acc1[4][8];
#pragma unroll
  for (int mf = 0; mf < 4; ++mf)
#pragma unroll
    for (int n = 0; n < 8; ++n) acc1[mf][n] = (f32x4){0.f,0.f,0.f,0.f};

  auto s1_load = [&](short8_t (&bb)[8], int ks) {
#pragma unroll
    for (int n = 0; n < 8; ++n)
      bb[n] = pb1[((w * 8 + n) * 4 + ks) * 64 + l];
  };
  auto s1_mfma = [&](short8_t (&bb)[8], int ks) {
    short8_t a[4];
#pragma unroll
    for (int mf = 0; mf < 4; ++mf) {
      int r = mf * 16 + lr;
      a[mf] = *(const short8_t*)((const char*)aT + r * 256 + ((ks * 64 + lk * 16) ^ ((r & 7) << 4)));
    }
#pragma unroll
    for (int mf = 0; mf < 4; ++mf)
#pragma unroll
      for (int n = 0; n < 8; ++n)
        acc1[mf][n] = __builtin_amdgcn_mfma_f32_16x16x32_bf16(a[mf], bb[n], acc1[mf][n], 0, 0, 0);
  };

  {
    short8_t bA[8], bB[8];
    s1_load(bA, 0);
    s1_load(bB, 1); s1_mfma(bA, 0);
    s1_load(bA, 2); s1_mfma(bB, 1);
    s1_load(bB, 3); s1_mfma(bA, 2);
    s1_mfma(bB, 3);
  }

  // epilogue: bias + relu + bf16 into swizzled t1 (own cols, all rows)
#pragma unroll
  for (int n = 0; n < 8; ++n) {
    int col = (w * 8 + n) * 16 + lr;
    float bb = b1[col];
#pragma unroll
    for (int mf = 0; mf < 4; ++mf)
#pragma unroll
      for (int r2 = 0; r2 < 4; ++r2) {
        int rr = mf * 16 + lk * 4 + r2;
        *(ushort*)((char*)t1 + rr * 1024 + ((col * 2) ^ ((rr & 7) << 4))) =
            f2bf(fmaxf(acc1[mf][n][r2] + bb, 0.f));
      }
  }
  __syncthreads();

  // ---- stage 2: c2[:, w*64:(w+1)*64] = t1 @ W2, K=512 ----
  const short8_t* pb2 = (const short8_t*)W2p;
  f32x4 acc2[4][4];
#pragma unroll
  for (int mf = 0; mf < 4; ++mf)
#pragma unroll
    for (int n = 0; n < 4; ++n) acc2[mf][n] = (f32x4){0.f,0.f,0.f,0.f};

  auto s2_load = [&](short8_t (&bb)[8], int p) {   // pair p: ks=2p,2p+1
#pragma unroll
    for (int n = 0; n < 4; ++n) {
      bb[n]     = pb2[((w * 4 + n) * 16 + 2 * p)     * 64 + l];
      bb[4 + n] = pb2[((w * 4 + n) * 16 + 2 * p + 1) * 64 + l];
    }
  };
  auto s2_mfma = [&](short8_t (&bb)[8], int p) {
#pragma unroll
    for (int h = 0; h < 2; ++h) {
      int ks = 2 * p + h;
      short8_t a[4];
#pragma unroll
      for (int mf = 0; mf < 4; ++mf) {
        int r = mf * 16 + lr;
        a[mf] = *(const short8_t*)((const char*)t1 + r * 1024 + ((ks * 64 + lk * 16) ^ ((r & 7) << 4)));
      }
#pragma unroll
      for (int mf = 0; mf < 4; ++mf)
#pragma unroll
        for (int n = 0; n < 4; ++n)
          acc2[mf][n] = __builtin_amdgcn_mfma_f32_16x16x32_bf16(a[mf], bb[h * 4 + n], acc2[mf][n], 0, 0, 0);
    }
  };

  {
    short8_t cA[8], cB[8];
    s2_load(cA, 0);
    s2_load(cB, 1); s2_mfma(cA, 0);
    s2_load(cA, 2); s2_mfma(cB, 1);
    s2_load(cB, 3); s2_mfma(cA, 2);
    s2_load(cA, 4); s2_mfma(cB, 3);
    s2_load(cB, 5); s2_mfma(cA, 4);
    s2_load(cA, 6); s2_mfma(cB, 5);
    s2_load(cB, 7); s2_mfma(cA, 6);
    s2_mfma(cB, 7);
  }

  // ---- stage 3 folded: po = relu(c2 + b2) @ W3 (partial over own 64 cols) ----
  float po[4][4];
#pragma unroll
  for (int mf = 0; mf < 4; ++mf)
#pragma unroll
    for (int r2 = 0; r2 < 4; ++r2) po[mf][r2] = 0.f;
#pragma unroll
  for (int n = 0; n < 4; ++n) {
    int col = (w * 4 + n) * 16 + lr;
    float bb = b2[col];
    float w3 = W3[col];
#pragma unroll
    for (int mf = 0; mf < 4; ++mf)
#pragma unroll
      for (int r2 = 0; r2 < 4; ++r2)
        po[mf][r2] += fmaxf(acc2[mf][n][r2] + bb, 0.f) * w3;
  }
#pragma unroll
  for (int mf = 0; mf < 4; ++mf)
#pragma unroll
    for (int r2 = 0; r2 < 4; ++r2) {
      float v = po[mf][r2];
      v += __shfl_xor(v, 1, 64);
      v += __shfl_xor(v, 2, 64);
      v += __shfl_xor(v, 4, 64);
      v += __shfl_xor(v, 8, 64);
      po[mf][r2] = v;
    }
  float* pf = (float*)aT;   // safe: all aT reads finished before stage-1 barrier
  if (lr == 0) {
#pragma unroll
    for (int mf = 0; mf < 4; ++mf)
#pragma unroll
      for (int r2 = 0; r2 < 4; ++r2)
        pf[w * 64 + mf * 16 + lk * 4 + r2] = po[mf][r2];
  }
  __syncthreads();
  if (t < 64) {
    int gr = row0 + t;
    if (gr < N)
      out[gr] = pf[t] + pf[64 + t] + pf[128 + t] + pf[192 + t] + b3[0];
  }
}

// ------------------------------- launcher ------------------------------------

extern "C" void kernel_launch(void* const* d_in, const int* in_sizes, int n_in,
                              void* d_out, int out_size, void* d_ws, size_t ws_size,
                              hipStream_t stream) {
  const float* x  = (const float*)d_in[0];
  const int*   ei = (const int*)d_in[1];
  const float* Wg = (const float*)d_in[2];
  const float* bg = (const float*)d_in[3];
  const float* W1 = (const float*)d_in[4];
  const float* b1 = (const float*)d_in[5];
  const float* W2 = (const float*)d_in[6];
  const float* b2 = (const float*)d_in[7];
  const float* W3 = (const float*)d_in[8];
  const float* b3 = (const float*)d_in[9];
  float* out = (float*)d_out;

  const int N = in_sizes[0] / DN;
  const int E = in_sizes[1] / 2;

  char* ws = (char*)d_ws;
  size_t off = 0;
  auto alloc = [&](size_t bytes) -> void* {
    void* p = ws + off;
    off = (off + bytes + 255) & ~(size_t)255;
    return p;
  };
  int*    deg    = (int*)alloc((size_t)N * 4);
  int*    ro     = (int*)alloc(((size_t)N + 1) * 4);
  int*    cursor = (int*)alloc((size_t)N * 4);
  int*    sums   = (int*)alloc(4096);
  float*  dinv   = (float*)alloc((size_t)N * 4);
  int*    csr    = (int*)alloc((size_t)E * 4);
  ushort* hsb    = (ushort*)alloc((size_t)N * DN * 2);
  ushort* aggb   = (ushort*)alloc((size_t)N * DN * 2);
  ushort* Wgp    = (ushort*)alloc((size_t)DN * DN * 2);
  ushort* W1p    = (ushort*)alloc((size_t)DN * H1N * 2);
  ushort* W2p    = (ushort*)alloc((size_t)H1N * H2N * 2);
  (void)ws_size; (void)n_in; (void)out_size;

  hipMemsetAsync(deg, 0, (size_t)N * 4, stream);

  k_deg<<<(E + 255) / 256, 256, 0, stream>>>(ei + E, deg, E);
  k_dinv<<<(N + 255) / 256, 256, 0, stream>>>(deg, dinv, N);

  int nb = (N + 255) / 256;
  k_scan_a<<<nb, 256, 0, stream>>>(deg, ro, sums, N);
  k_scan_b<<<1, 512, 0, stream>>>(sums, nb);
  k_scan_c<<<nb, 256, 0, stream>>>(ro, sums, cursor, N, E);
  k_csr<<<(E + 255) / 256, 256, 0, stream>>>(ei, cursor, csr, E);

  // weight repacks (bf16 fragment layout)
  k_pack<<<(DN / 32 * DN / 16 * 64 + 255) / 256, 256, 0, stream>>>(Wg, Wgp, DN, DN);
  k_pack<<<(DN / 32 * H1N / 16 * 64 + 255) / 256, 256, 0, stream>>>(W1, W1p, DN, H1N);
  k_pack<<<(H1N / 32 * H2N / 16 * 64 + 255) / 256, 256, 0, stream>>>(W2, W2p, H1N, H2N);

  int nb64 = (N + 63) / 64;
  k_gemm1<<<nb64, 256, 0, stream>>>(x, Wgp, dinv, hsb, N);
  k_agg<<<(N + 15) / 16, 256, 0, stream>>>(hsb, x, csr, ro, dinv, bg, aggb, N);
  k_mlp<<<nb64, 256, 0, stream>>>(aggb, W1p, b1, W2p, b2, W3, b3, out, N);
}

// Round 4
// 261.799 us; speedup vs baseline: 5.6536x; 1.3840x over previous
//
#include <hip/hip_runtime.h>

#define DN  128
#define H1N 512
#define H2N 256
#define TILE_A 4096

typedef __attribute__((ext_vector_type(8))) short short8_t;   // 8 bf16
typedef __attribute__((ext_vector_type(4))) float f32x4;      // MFMA acc

__device__ inline ushort f2bf(float f) {
  union { float f; unsigned u; } v; v.f = f;
  unsigned r = v.u + 0x7FFF + ((v.u >> 16) & 1);   // RNE
  return (ushort)(r >> 16);
}
__device__ inline float bf2f(ushort u) {
  union { unsigned u; float f; } v; v.u = ((unsigned)u) << 16;
  return v.f;
}

// ---------------- preprocessing: degree, dinv, scan ----------------

__global__ __launch_bounds__(256) void k_deg(const int* __restrict__ dst,
                                             int* __restrict__ deg, int E) {
  int e = blockIdx.x * 256 + threadIdx.x;
  if (e < E) atomicAdd(&deg[dst[e]], 1);
}

__global__ __launch_bounds__(256) void k_dinv(const int* __restrict__ deg,
                                              float* __restrict__ dinv, int N) {
  int i = blockIdx.x * 256 + threadIdx.x;
  if (i < N) dinv[i] = rsqrtf((float)(deg[i] + 1));  // +1 self-loop
}

__global__ __launch_bounds__(256) void k_scan_a(const int* __restrict__ deg,
                                                int* __restrict__ excl,
                                                int* __restrict__ sums, int N) {
  __shared__ int s[256];
  int t = threadIdx.x;
  int i = blockIdx.x * 256 + t;
  int v = (i < N) ? deg[i] : 0;
  s[t] = v; __syncthreads();
  for (int o = 1; o < 256; o <<= 1) {
    int a = (t >= o) ? s[t - o] : 0;
    __syncthreads();
    s[t] += a;
    __syncthreads();
  }
  if (i < N) excl[i] = s[t] - v;
  if (t == 255) sums[blockIdx.x] = s[255];
}

__global__ __launch_bounds__(512) void k_scan_b(int* __restrict__ sums, int nb) {
  __shared__ int s[512];
  int t = threadIdx.x;
  int v = (t < nb) ? sums[t] : 0;
  s[t] = v; __syncthreads();
  for (int o = 1; o < 512; o <<= 1) {
    int a = (t >= o) ? s[t - o] : 0;
    __syncthreads();
    s[t] += a;
    __syncthreads();
  }
  if (t < nb) sums[t] = s[t] - v;
}

__global__ __launch_bounds__(256) void k_scan_c(int* __restrict__ ro,
                                                const int* __restrict__ sums,
                                                int N, int E) {
  int i = blockIdx.x * 256 + threadIdx.x;
  if (i < N) ro[i] = ro[i] + sums[blockIdx.x];
  if (i == 0) ro[N] = E;
}

// -------- CSR build, phase 0: bucket write cursors = ro[b*256] --------

__global__ __launch_bounds__(256) void k_binit(const int* __restrict__ ro,
                                               int* __restrict__ bcur,
                                               int N, int NB) {
  int b = blockIdx.x * 256 + threadIdx.x;
  if (b < NB) bcur[b] = ro[min(b << 8, N)];
}

// -------- CSR build, pass A: tile-reorder bucketize (coalesced writes) -------
// Each block: 4096 edges -> LDS histogram by dst>>8 -> scan -> LDS reorder ->
// reserve global runs via one atomicAdd per bucket -> coalesced run write-out.

__global__ __launch_bounds__(256) void k_bucketA(const int* __restrict__ ei,
                                                 int* __restrict__ bcur,
                                                 uint2* __restrict__ pairs,
                                                 int E, int NB) {
  __shared__ int hist[512];
  __shared__ int start[512];
  __shared__ int cur[512];
  __shared__ int gbase[512];
  __shared__ uint2 lp[TILE_A];   // 32 KB
  int t = threadIdx.x;
  int base = blockIdx.x * TILE_A;
  int cnt = E - base; if (cnt > TILE_A) cnt = TILE_A;

  for (int i = t; i < 512; i += 256) hist[i] = 0;
  __syncthreads();

  int sreg[16], dreg[16];
#pragma unroll
  for (int k = 0; k < 16; ++k) {
    int idx = t + 256 * k;
    bool v = idx < cnt;
    sreg[k] = v ? ei[base + idx] : 0;
    dreg[k] = v ? ei[E + base + idx] : -1;
    if (v) atomicAdd(&hist[dreg[k] >> 8], 1);
  }
  __syncthreads();

  // inclusive Hillis-Steele over 512 entries (2 per thread), then exclusive
  for (int i = t; i < 512; i += 256) start[i] = hist[i];
  __syncthreads();
  for (int o = 1; o < 512; o <<= 1) {
    int i0 = t, i1 = t + 256;
    int v0 = (i0 >= o) ? start[i0 - o] : 0;
    int v1 = (i1 >= o) ? start[i1 - o] : 0;
    __syncthreads();
    start[i0] += v0;
    start[i1] += v1;
    __syncthreads();
  }
  for (int i = t; i < 512; i += 256) start[i] -= hist[i];  // exclusive
  __syncthreads();
  for (int i = t; i < 512; i += 256) cur[i] = start[i];
  __syncthreads();

#pragma unroll
  for (int k = 0; k < 16; ++k) {
    if (dreg[k] >= 0) {
      int d = dreg[k] >> 8;
      int p = atomicAdd(&cur[d], 1);
      lp[p] = make_uint2((unsigned)sreg[k], (unsigned)dreg[k]);
    }
  }
  __syncthreads();

  for (int i = t; i < NB; i += 256)
    gbase[i] = hist[i] ? atomicAdd(&bcur[i], hist[i]) : 0;
  __syncthreads();

  for (int p = t; p < cnt; p += 256) {
    uint2 pr = lp[p];
    int d = (int)(pr.y >> 8);
    pairs[gbase[d] + (p - start[d])] = pr;
  }
}

// -------- CSR build, pass B: per-bucket node sort, coalesced csr write -------

__global__ __launch_bounds__(256) void k_bucketB(const uint2* __restrict__ pairs,
                                                 const int* __restrict__ ro,
                                                 int* __restrict__ csr,
                                                 int N) {
  __shared__ int cur[256];
  __shared__ int lout[6144];   // 24 KB; mean bucket = 4096, 6144 = +32 sigma
  int b = blockIdx.x;
  int t = threadIdx.x;
  int n0 = b << 8;
  int n1 = n0 + 256; if (n1 > N) n1 = N;
  int ro0 = ro[n0];
  int cnt = ro[n1] - ro0;

  int n = n0 + t;
  cur[t] = (n < N) ? (ro[n] - ro0) : cnt;
  __syncthreads();

  for (int k = t; k < cnt; k += 256) {
    uint2 pr = pairs[ro0 + k];
    int local = (int)(pr.y & 255u);
    int p = atomicAdd(&cur[local], 1);
    lout[p] = (int)pr.x;
  }
  __syncthreads();
  for (int k = t; k < cnt; k += 256) csr[ro0 + k] = lout[k];
}

// ------------- weight repack into MFMA B-fragment order (bf16) ---------------

__global__ __launch_bounds__(256) void k_pack(const float* __restrict__ W,
                                              ushort* __restrict__ Wp,
                                              int K, int Ncols) {
  int idx = blockIdx.x * 256 + threadIdx.x;
  int ksn = K >> 5;
  int total = (Ncols >> 4) * ksn * 64;
  if (idx >= total) return;
  int l  = idx & 63;
  int ks = (idx >> 6) % ksn;
  int ct = idx / (64 * ksn);
  int col = ct * 16 + (l & 15);
  int kb  = ks * 32 + (l >> 4) * 8;
  short8_t v;
#pragma unroll
  for (int r = 0; r < 8; ++r)
    v[r] = (short)f2bf(W[(size_t)(kb + r) * Ncols + col]);
  *(short8_t*)&Wp[(size_t)idx * 8] = v;
}

// ---------------- GEMM1: hs = (x @ W_gcn) * dinv[row]  (bf16 out) ------------

__global__ __launch_bounds__(256, 4) void k_gemm1(const float* __restrict__ x,
                                                  const ushort* __restrict__ Wgp,
                                                  const float* __restrict__ dinv,
                                                  ushort* __restrict__ hs, int N) {
  __shared__ ushort xT[64 * 128];  // bf16, XOR-swizzled, 16 KB
  int t = threadIdx.x;
  int row0 = blockIdx.x * 64;

#pragma unroll
  for (int i = 0; i < 4; ++i) {
    int c = t + 256 * i;
    int r = c >> 4, d0 = (c & 15) * 8;
    int gr = row0 + r;
    float4 v0 = {0,0,0,0}, v1 = {0,0,0,0};
    if (gr < N) {
      v0 = *(const float4*)(x + (size_t)gr * DN + d0);
      v1 = *(const float4*)(x + (size_t)gr * DN + d0 + 4);
    }
    short8_t p;
    p[0]=(short)f2bf(v0.x); p[1]=(short)f2bf(v0.y); p[2]=(short)f2bf(v0.z); p[3]=(short)f2bf(v0.w);
    p[4]=(short)f2bf(v1.x); p[5]=(short)f2bf(v1.y); p[6]=(short)f2bf(v1.z); p[7]=(short)f2bf(v1.w);
    *(short8_t*)((char*)xT + r * 256 + ((d0 * 2) ^ ((r & 7) << 4))) = p;
  }
  __syncthreads();

  int w = t >> 6, l = t & 63;
  int lr = l & 15, lk = l >> 4;
  const short8_t* pbg = (const short8_t*)Wgp;

  f32x4 acc[4][2];
#pragma unroll
  for (int mf = 0; mf < 4; ++mf)
#pragma unroll
    for (int n = 0; n < 2; ++n) acc[mf][n] = (f32x4){0.f,0.f,0.f,0.f};

  auto g_load = [&](short8_t (&bb)[2], int ks) {
#pragma unroll
    for (int n = 0; n < 2; ++n)
      bb[n] = pbg[((w * 2 + n) * 4 + ks) * 64 + l];
  };
  auto g_mfma = [&](short8_t (&bb)[2], int ks) {
    short8_t a[4];
#pragma unroll
    for (int mf = 0; mf < 4; ++mf) {
      int r = mf * 16 + lr;
      a[mf] = *(const short8_t*)((const char*)xT + r * 256 + ((ks * 64 + lk * 16) ^ ((r & 7) << 4)));
    }
#pragma unroll
    for (int mf = 0; mf < 4; ++mf)
#pragma unroll
      for (int n = 0; n < 2; ++n)
        acc[mf][n] = __builtin_amdgcn_mfma_f32_16x16x32_bf16(a[mf], bb[n], acc[mf][n], 0, 0, 0);
  };

  short8_t bA[2], bB[2];
  g_load(bA, 0);
  g_load(bB, 1); g_mfma(bA, 0);
  g_load(bA, 2); g_mfma(bB, 1);
  g_load(bB, 3); g_mfma(bA, 2);
  g_mfma(bB, 3);

  float dv[4][4];
#pragma unroll
  for (int mf = 0; mf < 4; ++mf)
#pragma unroll
    for (int r2 = 0; r2 < 4; ++r2) {
      int gr = row0 + mf * 16 + lk * 4 + r2;
      dv[mf][r2] = (gr < N) ? dinv[gr] : 0.f;
    }
#pragma unroll
  for (int n = 0; n < 2; ++n) {
    int col = (w * 2 + n) * 16 + lr;
#pragma unroll
    for (int mf = 0; mf < 4; ++mf)
#pragma unroll
      for (int r2 = 0; r2 < 4; ++r2) {
        int gr = row0 + mf * 16 + lk * 4 + r2;
        if (gr < N) hs[(size_t)gr * DN + col] = f2bf(acc[mf][n][r2] * dv[mf][r2]);
      }
  }
}

// --------- aggregation: agg = bf16(relu(dinv*(sum+self) + b) + x) ------------

__global__ __launch_bounds__(256) void k_agg(const ushort* __restrict__ hs,
                                             const float* __restrict__ x,
                                             const int* __restrict__ csr,
                                             const int* __restrict__ ro,
                                             const float* __restrict__ dinv,
                                             const float* __restrict__ bg,
                                             ushort* __restrict__ aggb, int N) {
  int t = threadIdx.x;
  int node = blockIdx.x * 16 + (t >> 4);
  if (node >= N) return;
  int d0 = (t & 15) * 8;

  float s[8];
#pragma unroll
  for (int i = 0; i < 8; ++i) s[i] = 0.f;

  auto accum = [&](uint4 v) {
    s[0] += bf2f((ushort)(v.x & 0xffff)); s[1] += bf2f((ushort)(v.x >> 16));
    s[2] += bf2f((ushort)(v.y & 0xffff)); s[3] += bf2f((ushort)(v.y >> 16));
    s[4] += bf2f((ushort)(v.z & 0xffff)); s[5] += bf2f((ushort)(v.z >> 16));
    s[6] += bf2f((ushort)(v.w & 0xffff)); s[7] += bf2f((ushort)(v.w >> 16));
  };

  int beg = ro[node], end = ro[node + 1];
  int e = beg;
  for (; e + 2 <= end; e += 2) {
    int s0 = csr[e], s1 = csr[e + 1];
    uint4 v0 = *(const uint4*)(hs + (size_t)s0 * DN + d0);
    uint4 v1 = *(const uint4*)(hs + (size_t)s1 * DN + d0);
    accum(v0); accum(v1);
  }
  if (e < end) {
    int s0 = csr[e];
    accum(*(const uint4*)(hs + (size_t)s0 * DN + d0));
  }
  accum(*(const uint4*)(hs + (size_t)node * DN + d0));  // self (pre-scaled)

  float dn = dinv[node];
  float4 x0 = *(const float4*)(x + (size_t)node * DN + d0);
  float4 x1 = *(const float4*)(x + (size_t)node * DN + d0 + 4);
  float4 b0 = *(const float4*)(bg + d0);
  float4 b1v = *(const float4*)(bg + d0 + 4);
  float xv[8] = {x0.x, x0.y, x0.z, x0.w, x1.x, x1.y, x1.z, x1.w};
  float bv[8] = {b0.x, b0.y, b0.z, b0.w, b1v.x, b1v.y, b1v.z, b1v.w};
  uint outp[4];
#pragma unroll
  for (int i = 0; i < 4; ++i) {
    ushort lo = f2bf(fmaxf(s[2*i]   * dn + bv[2*i],   0.f) + xv[2*i]);
    ushort hi = f2bf(fmaxf(s[2*i+1] * dn + bv[2*i+1], 0.f) + xv[2*i+1]);
    outp[i] = (uint)lo | ((uint)hi << 16);
  }
  *(uint4*)(aggb + (size_t)node * DN + d0) = *(uint4*)outp;
}

// ------------- fused MFMA MLP: out = relu(relu(a@W1+b1)@W2+b2)@W3+b3 ---------

__global__ __launch_bounds__(256, 2) void k_mlp(const ushort* __restrict__ aggb,
                                                const ushort* __restrict__ W1p,
                                                const float* __restrict__ b1,
                                                const ushort* __restrict__ W2p,
                                                const float* __restrict__ b2,
                                                const float* __restrict__ W3,
                                                const float* __restrict__ b3,
                                                float* __restrict__ out, int N) {
  __shared__ ushort aT[64 * 128];   // 16 KB (reused as pf[4][64] floats later)
  __shared__ ushort t1[64 * 512];   // 64 KB
  int t = threadIdx.x;
  int row0 = blockIdx.x * 64;

#pragma unroll
  for (int i = 0; i < 4; ++i) {
    int c = t + 256 * i;
    int r = c >> 4;
    int cb = (c & 15) * 16;
    int gr = row0 + r;
    uint4 v = {0, 0, 0, 0};
    if (gr < N) v = *(const uint4*)(aggb + (size_t)gr * DN + (c & 15) * 8);
    *(uint4*)((char*)aT + r * 256 + (cb ^ ((r & 7) << 4))) = v;
  }
  __syncthreads();

  int w = t >> 6, l = t & 63;
  int lr = l & 15, lk = l >> 4;

  // ---- stage 1: t1[:, w*128:(w+1)*128) = relu(a @ W1 + b1) ----
  const short8_t* pb1 = (const short8_t*)W1p;
  f32x4 acc1[4][8];
#pragma unroll
  for (int mf = 0; mf < 4; ++mf)
#pragma unroll
    for (int n = 0; n < 8; ++n) acc1[mf][n] = (f32x4){0.f,0.f,0.f,0.f};

  auto s1_load = [&](short8_t (&bb)[8], int ks) {
#pragma unroll
    for (int n = 0; n < 8; ++n)
      bb[n] = pb1[((w * 8 + n) * 4 + ks) * 64 + l];
  };
  auto s1_mfma = [&](short8_t (&bb)[8], int ks) {
    short8_t a[4];
#pragma unroll
    for (int mf = 0; mf < 4; ++mf) {
      int r = mf * 16 + lr;
      a[mf] = *(const short8_t*)((const char*)aT + r * 256 + ((ks * 64 + lk * 16) ^ ((r & 7) << 4)));
    }
#pragma unroll
    for (int mf = 0; mf < 4; ++mf)
#pragma unroll
      for (int n = 0; n < 8; ++n)
        acc1[mf][n] = __builtin_amdgcn_mfma_f32_16x16x32_bf16(a[mf], bb[n], acc1[mf][n], 0, 0, 0);
  };

  {
    short8_t bA[8], bB[8];
    s1_load(bA, 0);
    s1_load(bB, 1); s1_mfma(bA, 0);
    s1_load(bA, 2); s1_mfma(bB, 1);
    s1_load(bB, 3); s1_mfma(bA, 2);
    s1_mfma(bB, 3);
  }

#pragma unroll
  for (int n = 0; n < 8; ++n) {
    int col = (w * 8 + n) * 16 + lr;
    float bb = b1[col];
#pragma unroll
    for (int mf = 0; mf < 4; ++mf)
#pragma unroll
      for (int r2 = 0; r2 < 4; ++r2) {
        int rr = mf * 16 + lk * 4 + r2;
        *(ushort*)((char*)t1 + rr * 1024 + ((col * 2) ^ ((rr & 7) << 4))) =
            f2bf(fmaxf(acc1[mf][n][r2] + bb, 0.f));
      }
  }
  __syncthreads();

  // ---- stage 2: c2[:, w*64:(w+1)*64) = t1 @ W2, K=512 ----
  const short8_t* pb2 = (const short8_t*)W2p;
  f32x4 acc2[4][4];
#pragma unroll
  for (int mf = 0; mf < 4; ++mf)
#pragma unroll
    for (int n = 0; n < 4; ++n) acc2[mf][n] = (f32x4){0.f,0.f,0.f,0.f};

  auto s2_load = [&](short8_t (&bb)[8], int p) {
#pragma unroll
    for (int n = 0; n < 4; ++n) {
      bb[n]     = pb2[((w * 4 + n) * 16 + 2 * p)     * 64 + l];
      bb[4 + n] = pb2[((w * 4 + n) * 16 + 2 * p + 1) * 64 + l];
    }
  };
  auto s2_mfma = [&](short8_t (&bb)[8], int p) {
#pragma unroll
    for (int h = 0; h < 2; ++h) {
      int ks = 2 * p + h;
      short8_t a[4];
#pragma unroll
      for (int mf = 0; mf < 4; ++mf) {
        int r = mf * 16 + lr;
        a[mf] = *(const short8_t*)((const char*)t1 + r * 1024 + ((ks * 64 + lk * 16) ^ ((r & 7) << 4)));
      }
#pragma unroll
      for (int mf = 0; mf < 4; ++mf)
#pragma unroll
        for (int n = 0; n < 4; ++n)
          acc2[mf][n] = __builtin_amdgcn_mfma_f32_16x16x32_bf16(a[mf], bb[h * 4 + n], acc2[mf][n], 0, 0, 0);
    }
  };

  {
    short8_t cA[8], cB[8];
    s2_load(cA, 0);
    s2_load(cB, 1); s2_mfma(cA, 0);
    s2_load(cA, 2); s2_mfma(cB, 1);
    s2_load(cB, 3); s2_mfma(cA, 2);
    s2_load(cA, 4); s2_mfma(cB, 3);
    s2_load(cB, 5); s2_mfma(cA, 4);
    s2_load(cA, 6); s2_mfma(cB, 5);
    s2_load(cB, 7); s2_mfma(cA, 6);
    s2_mfma(cB, 7);
  }

  // ---- stage 3 folded: po = relu(c2 + b2) @ W3 (partial over own 64 cols) ----
  float po[4][4];
#pragma unroll
  for (int mf = 0; mf < 4; ++mf)
#pragma unroll
    for (int r2 = 0; r2 < 4; ++r2) po[mf][r2] = 0.f;
#pragma unroll
  for (int n = 0; n < 4; ++n) {
    int col = (w * 4 + n) * 16 + lr;
    float bb = b2[col];
    float w3 = W3[col];
#pragma unroll
    for (int mf = 0; mf < 4; ++mf)
#pragma unroll
      for (int r2 = 0; r2 < 4; ++r2)
        po[mf][r2] += fmaxf(acc2[mf][n][r2] + bb, 0.f) * w3;
  }
#pragma unroll
  for (int mf = 0; mf < 4; ++mf)
#pragma unroll
    for (int r2 = 0; r2 < 4; ++r2) {
      float v = po[mf][r2];
      v += __shfl_xor(v, 1, 64);
      v += __shfl_xor(v, 2, 64);
      v += __shfl_xor(v, 4, 64);
      v += __shfl_xor(v, 8, 64);
      po[mf][r2] = v;
    }
  float* pf = (float*)aT;
  if (lr == 0) {
#pragma unroll
    for (int mf = 0; mf < 4; ++mf)
#pragma unroll
      for (int r2 = 0; r2 < 4; ++r2)
        pf[w * 64 + mf * 16 + lk * 4 + r2] = po[mf][r2];
  }
  __syncthreads();
  if (t < 64) {
    int gr = row0 + t;
    if (gr < N)
      out[gr] = pf[t] + pf[64 + t] + pf[128 + t] + pf[192 + t] + b3[0];
  }
}

// ------------------------------- launcher ------------------------------------

extern "C" void kernel_launch(void* const* d_in, const int* in_sizes, int n_in,
                              void* d_out, int out_size, void* d_ws, size_t ws_size,
                              hipStream_t stream) {
  const float* x  = (const float*)d_in[0];
  const int*   ei = (const int*)d_in[1];
  const float* Wg = (const float*)d_in[2];
  const float* bg = (const float*)d_in[3];
  const float* W1 = (const float*)d_in[4];
  const float* b1 = (const float*)d_in[5];
  const float* W2 = (const float*)d_in[6];
  const float* b2 = (const float*)d_in[7];
  const float* W3 = (const float*)d_in[8];
  const float* b3 = (const float*)d_in[9];
  float* out = (float*)d_out;

  const int N = in_sizes[0] / DN;
  const int E = in_sizes[1] / 2;
  const int NB = (N + 255) >> 8;

  char* ws = (char*)d_ws;
  size_t off = 0;
  auto alloc = [&](size_t bytes) -> void* {
    void* p = ws + off;
    off = (off + bytes + 255) & ~(size_t)255;
    return p;
  };
  int*    deg    = (int*)alloc((size_t)N * 4);
  int*    ro     = (int*)alloc(((size_t)N + 1) * 4);
  int*    sums   = (int*)alloc(4096);
  int*    bcur   = (int*)alloc((size_t)NB * 4);
  float*  dinv   = (float*)alloc((size_t)N * 4);
  int*    csr    = (int*)alloc((size_t)E * 4);
  uint2*  pairs  = (uint2*)alloc((size_t)E * 8);
  ushort* hsb    = (ushort*)alloc((size_t)N * DN * 2);
  ushort* aggb   = (ushort*)alloc((size_t)N * DN * 2);
  ushort* Wgp    = (ushort*)alloc((size_t)DN * DN * 2);
  ushort* W1p    = (ushort*)alloc((size_t)DN * H1N * 2);
  ushort* W2p    = (ushort*)alloc((size_t)H1N * H2N * 2);
  (void)ws_size; (void)n_in; (void)out_size;

  hipMemsetAsync(deg, 0, (size_t)N * 4, stream);

  k_deg<<<(E + 255) / 256, 256, 0, stream>>>(ei + E, deg, E);
  k_dinv<<<(N + 255) / 256, 256, 0, stream>>>(deg, dinv, N);

  int nb = (N + 255) / 256;
  k_scan_a<<<nb, 256, 0, stream>>>(deg, ro, sums, N);
  k_scan_b<<<1, 512, 0, stream>>>(sums, nb);
  k_scan_c<<<nb, 256, 0, stream>>>(ro, sums, N, E);

  k_binit<<<(NB + 255) / 256, 256, 0, stream>>>(ro, bcur, N, NB);
  k_bucketA<<<(E + TILE_A - 1) / TILE_A, 256, 0, stream>>>(ei, bcur, pairs, E, NB);
  k_bucketB<<<NB, 256, 0, stream>>>(pairs, ro, csr, N);

  k_pack<<<(DN / 32 * DN / 16 * 64 + 255) / 256, 256, 0, stream>>>(Wg, Wgp, DN, DN);
  k_pack<<<(DN / 32 * H1N / 16 * 64 + 255) / 256, 256, 0, stream>>>(W1, W1p, DN, H1N);
  k_pack<<<(H1N / 32 * H2N / 16 * 64 + 255) / 256, 256, 0, stream>>>(W2, W2p, H1N, H2N);

  int nb64 = (N + 63) / 64;
  k_gemm1<<<nb64, 256, 0, stream>>>(x, Wgp, dinv, hsb, N);
  k_agg<<<(N + 15) / 16, 256, 0, stream>>>(hsb, x, csr, ro, dinv, bg, aggb, N);
  k_mlp<<<nb64, 256, 0, stream>>>(aggb, W1p, b1, W2p, b2, W3, b3, out, N);
}

// Round 5
// 259.016 us; speedup vs baseline: 5.7144x; 1.0107x over previous
//
#include <hip/hip_runtime.h>

#define DN  128
#define H1N 512
#define H2N 256
#define TILE_A 4096

typedef __attribute__((ext_vector_type(8))) short short8_t;   // 8 bf16
typedef __attribute__((ext_vector_type(4))) float f32x4;      // MFMA acc

__device__ inline ushort f2bf(float f) {
  union { float f; unsigned u; } v; v.f = f;
  unsigned r = v.u + 0x7FFF + ((v.u >> 16) & 1);   // RNE
  return (ushort)(r >> 16);
}
__device__ inline float bf2f(ushort u) {
  union { unsigned u; float f; } v; v.u = ((unsigned)u) << 16;
  return v.f;
}
__device__ inline float asf(unsigned u) {
  union { unsigned u; float f; } v; v.u = u;
  return v.f;
}

// ---------------- preprocessing: degree, dinv, scan ----------------

__global__ __launch_bounds__(256) void k_deg(const int* __restrict__ dst,
                                             int* __restrict__ deg, int E) {
  int e = blockIdx.x * 256 + threadIdx.x;
  if (e < E) atomicAdd(&deg[dst[e]], 1);
}

__global__ __launch_bounds__(256) void k_scan_a(const int* __restrict__ deg,
                                                int* __restrict__ excl,
                                                int* __restrict__ sums,
                                                float* __restrict__ dinv, int N) {
  __shared__ int s[256];
  int t = threadIdx.x;
  int i = blockIdx.x * 256 + t;
  int v = (i < N) ? deg[i] : 0;
  if (i < N) dinv[i] = rsqrtf((float)(v + 1));  // +1 self-loop
  s[t] = v; __syncthreads();
  for (int o = 1; o < 256; o <<= 1) {
    int a = (t >= o) ? s[t - o] : 0;
    __syncthreads();
    s[t] += a;
    __syncthreads();
  }
  if (i < N) excl[i] = s[t] - v;
  if (t == 255) sums[blockIdx.x] = s[255];
}

__global__ __launch_bounds__(512) void k_scan_b(int* __restrict__ sums, int nb) {
  __shared__ int s[512];
  int t = threadIdx.x;
  int v = (t < nb) ? sums[t] : 0;
  s[t] = v; __syncthreads();
  for (int o = 1; o < 512; o <<= 1) {
    int a = (t >= o) ? s[t - o] : 0;
    __syncthreads();
    s[t] += a;
    __syncthreads();
  }
  if (t < nb) sums[t] = s[t] - v;
}

__global__ __launch_bounds__(256) void k_scan_c(int* __restrict__ ro,
                                                const int* __restrict__ sums,
                                                int N, int E) {
  int i = blockIdx.x * 256 + threadIdx.x;
  if (i < N) ro[i] = ro[i] + sums[blockIdx.x];
  if (i == 0) ro[N] = E;
}

// -------- CSR build, phase 0: bucket write cursors = ro[b*256] --------

__global__ __launch_bounds__(256) void k_binit(const int* __restrict__ ro,
                                               int* __restrict__ bcur,
                                               int N, int NB) {
  int b = blockIdx.x * 256 + threadIdx.x;
  if (b < NB) bcur[b] = ro[min(b << 8, N)];
}

// -------- CSR build, pass A: tile-reorder bucketize (coalesced writes) -------

__global__ __launch_bounds__(256) void k_bucketA(const int* __restrict__ ei,
                                                 int* __restrict__ bcur,
                                                 uint2* __restrict__ pairs,
                                                 int E, int NB) {
  __shared__ int hist[512];
  __shared__ int start[512];
  __shared__ int cur[512];
  __shared__ int gbase[512];
  __shared__ uint2 lp[TILE_A];   // 32 KB
  int t = threadIdx.x;
  int base = blockIdx.x * TILE_A;
  int cnt = E - base; if (cnt > TILE_A) cnt = TILE_A;

  for (int i = t; i < 512; i += 256) hist[i] = 0;
  __syncthreads();

  int sreg[16], dreg[16];
#pragma unroll
  for (int k = 0; k < 16; ++k) {
    int idx = t + 256 * k;
    bool v = idx < cnt;
    sreg[k] = v ? ei[base + idx] : 0;
    dreg[k] = v ? ei[E + base + idx] : -1;
    if (v) atomicAdd(&hist[dreg[k] >> 8], 1);
  }
  __syncthreads();

  for (int i = t; i < 512; i += 256) start[i] = hist[i];
  __syncthreads();
  for (int o = 1; o < 512; o <<= 1) {
    int i0 = t, i1 = t + 256;
    int v0 = (i0 >= o) ? start[i0 - o] : 0;
    int v1 = (i1 >= o) ? start[i1 - o] : 0;
    __syncthreads();
    start[i0] += v0;
    start[i1] += v1;
    __syncthreads();
  }
  for (int i = t; i < 512; i += 256) start[i] -= hist[i];  // exclusive
  __syncthreads();
  for (int i = t; i < 512; i += 256) cur[i] = start[i];
  __syncthreads();

#pragma unroll
  for (int k = 0; k < 16; ++k) {
    if (dreg[k] >= 0) {
      int d = dreg[k] >> 8;
      int p = atomicAdd(&cur[d], 1);
      lp[p] = make_uint2((unsigned)sreg[k], (unsigned)dreg[k]);
    }
  }
  __syncthreads();

  for (int i = t; i < NB; i += 256)
    gbase[i] = hist[i] ? atomicAdd(&bcur[i], hist[i]) : 0;
  __syncthreads();

  for (int p = t; p < cnt; p += 256) {
    uint2 pr = lp[p];
    int d = (int)(pr.y >> 8);
    pairs[gbase[d] + (p - start[d])] = pr;
  }
}

// -------- CSR build, pass B: per-bucket node sort, coalesced csr write -------

__global__ __launch_bounds__(256) void k_bucketB(const uint2* __restrict__ pairs,
                                                 const int* __restrict__ ro,
                                                 int* __restrict__ csr,
                                                 int N) {
  __shared__ int cur[256];
  __shared__ int lout[6144];   // 24 KB
  int b = blockIdx.x;
  int t = threadIdx.x;
  int n0 = b << 8;
  int n1 = n0 + 256; if (n1 > N) n1 = N;
  int ro0 = ro[n0];
  int cnt = ro[n1] - ro0;

  int n = n0 + t;
  cur[t] = (n < N) ? (ro[n] - ro0) : cnt;
  __syncthreads();

  for (int k = t; k < cnt; k += 256) {
    uint2 pr = pairs[ro0 + k];
    int local = (int)(pr.y & 255u);
    int p = atomicAdd(&cur[local], 1);
    lout[p] = (int)pr.x;
  }
  __syncthreads();
  for (int k = t; k < cnt; k += 256) csr[ro0 + k] = lout[k];
}

// ------------- weight repack into MFMA B-fragment order (bf16) ---------------

__global__ __launch_bounds__(256) void k_pack(const float* __restrict__ W,
                                              ushort* __restrict__ Wp,
                                              int K, int Ncols) {
  int idx = blockIdx.x * 256 + threadIdx.x;
  int ksn = K >> 5;
  int total = (Ncols >> 4) * ksn * 64;
  if (idx >= total) return;
  int l  = idx & 63;
  int ks = (idx >> 6) % ksn;
  int ct = idx / (64 * ksn);
  int col = ct * 16 + (l & 15);
  int kb  = ks * 32 + (l >> 4) * 8;
  short8_t v;
#pragma unroll
  for (int r = 0; r < 8; ++r)
    v[r] = (short)f2bf(W[(size_t)(kb + r) * Ncols + col]);
  *(short8_t*)&Wp[(size_t)idx * 8] = v;
}

// ---------------- GEMM1: hs = (x @ W_gcn) * dinv[row]  (bf16 out) ------------

__global__ __launch_bounds__(256, 4) void k_gemm1(const float* __restrict__ x,
                                                  const ushort* __restrict__ Wgp,
                                                  const float* __restrict__ dinv,
                                                  ushort* __restrict__ hs, int N) {
  __shared__ ushort xT[64 * 128];  // bf16, XOR-swizzled, 16 KB
  int t = threadIdx.x;
  int row0 = blockIdx.x * 64;

#pragma unroll
  for (int i = 0; i < 4; ++i) {
    int c = t + 256 * i;
    int r = c >> 4, d0 = (c & 15) * 8;
    int gr = row0 + r;
    float4 v0 = {0,0,0,0}, v1 = {0,0,0,0};
    if (gr < N) {
      v0 = *(const float4*)(x + (size_t)gr * DN + d0);
      v1 = *(const float4*)(x + (size_t)gr * DN + d0 + 4);
    }
    short8_t p;
    p[0]=(short)f2bf(v0.x); p[1]=(short)f2bf(v0.y); p[2]=(short)f2bf(v0.z); p[3]=(short)f2bf(v0.w);
    p[4]=(short)f2bf(v1.x); p[5]=(short)f2bf(v1.y); p[6]=(short)f2bf(v1.z); p[7]=(short)f2bf(v1.w);
    *(short8_t*)((char*)xT + r * 256 + ((d0 * 2) ^ ((r & 7) << 4))) = p;
  }
  __syncthreads();

  int w = t >> 6, l = t & 63;
  int lr = l & 15, lk = l >> 4;
  const short8_t* pbg = (const short8_t*)Wgp;

  f32x4 acc[4][2];
#pragma unroll
  for (int mf = 0; mf < 4; ++mf)
#pragma unroll
    for (int n = 0; n < 2; ++n) acc[mf][n] = (f32x4){0.f,0.f,0.f,0.f};

  auto g_load = [&](short8_t (&bb)[2], int ks) {
#pragma unroll
    for (int n = 0; n < 2; ++n)
      bb[n] = pbg[((w * 2 + n) * 4 + ks) * 64 + l];
  };
  auto g_mfma = [&](short8_t (&bb)[2], int ks) {
    short8_t a[4];
#pragma unroll
    for (int mf = 0; mf < 4; ++mf) {
      int r = mf * 16 + lr;
      a[mf] = *(const short8_t*)((const char*)xT + r * 256 + ((ks * 64 + lk * 16) ^ ((r & 7) << 4)));
    }
#pragma unroll
    for (int mf = 0; mf < 4; ++mf)
#pragma unroll
      for (int n = 0; n < 2; ++n)
        acc[mf][n] = __builtin_amdgcn_mfma_f32_16x16x32_bf16(a[mf], bb[n], acc[mf][n], 0, 0, 0);
  };

  short8_t bA[2], bB[2];
  g_load(bA, 0);
  g_load(bB, 1); g_mfma(bA, 0);
  g_load(bA, 2); g_mfma(bB, 1);
  g_load(bB, 3); g_mfma(bA, 2);
  g_mfma(bB, 3);

  float dv[4][4];
#pragma unroll
  for (int mf = 0; mf < 4; ++mf)
#pragma unroll
    for (int r2 = 0; r2 < 4; ++r2) {
      int gr = row0 + mf * 16 + lk * 4 + r2;
      dv[mf][r2] = (gr < N) ? dinv[gr] : 0.f;
    }
#pragma unroll
  for (int n = 0; n < 2; ++n) {
    int col = (w * 2 + n) * 16 + lr;
#pragma unroll
    for (int mf = 0; mf < 4; ++mf)
#pragma unroll
      for (int r2 = 0; r2 < 4; ++r2) {
        int gr = row0 + mf * 16 + lk * 4 + r2;
        if (gr < N) hs[(size_t)gr * DN + col] = f2bf(acc[mf][n][r2] * dv[mf][r2]);
      }
  }
}

// --------- aggregation: agg = bf16(relu(dinv*(sum+self) + b) + x) ------------
// 16 nodes/block, 16 lanes/node, 8 dims (uint4) per lane. 4-deep gather unroll.

__global__ __launch_bounds__(256) void k_agg(const ushort* __restrict__ hs,
                                             const float* __restrict__ x,
                                             const int* __restrict__ csr,
                                             const int* __restrict__ ro,
                                             const float* __restrict__ dinv,
                                             const float* __restrict__ bg,
                                             ushort* __restrict__ aggb, int N) {
  int t = threadIdx.x;
  int node = blockIdx.x * 16 + (t >> 4);
  if (node >= N) return;
  int d0 = (t & 15) * 8;

  // hoist epilogue loads so they overlap the gather loop
  int beg = ro[node], end = ro[node + 1];
  float dn = dinv[node];
  uint4 selfv = *(const uint4*)(hs + (size_t)node * DN + d0);
  float4 x0 = *(const float4*)(x + (size_t)node * DN + d0);
  float4 x1 = *(const float4*)(x + (size_t)node * DN + d0 + 4);
  float4 b0 = *(const float4*)(bg + d0);
  float4 b1v = *(const float4*)(bg + d0 + 4);

  float s[8];
#pragma unroll
  for (int i = 0; i < 8; ++i) s[i] = 0.f;

  auto accum = [&](uint4 v) {
    s[0] += asf(v.x << 16); s[1] += asf(v.x & 0xffff0000u);
    s[2] += asf(v.y << 16); s[3] += asf(v.y & 0xffff0000u);
    s[4] += asf(v.z << 16); s[5] += asf(v.z & 0xffff0000u);
    s[6] += asf(v.w << 16); s[7] += asf(v.w & 0xffff0000u);
  };

  int e = beg;
  for (; e + 4 <= end; e += 4) {
    int i0 = csr[e], i1 = csr[e + 1], i2 = csr[e + 2], i3 = csr[e + 3];
    uint4 v0 = *(const uint4*)(hs + (size_t)i0 * DN + d0);
    uint4 v1 = *(const uint4*)(hs + (size_t)i1 * DN + d0);
    uint4 v2 = *(const uint4*)(hs + (size_t)i2 * DN + d0);
    uint4 v3 = *(const uint4*)(hs + (size_t)i3 * DN + d0);
    accum(v0); accum(v1); accum(v2); accum(v3);
  }
  if (e + 2 <= end) {
    int i0 = csr[e], i1 = csr[e + 1];
    uint4 v0 = *(const uint4*)(hs + (size_t)i0 * DN + d0);
    uint4 v1 = *(const uint4*)(hs + (size_t)i1 * DN + d0);
    accum(v0); accum(v1);
    e += 2;
  }
  if (e < end) {
    int i0 = csr[e];
    accum(*(const uint4*)(hs + (size_t)i0 * DN + d0));
  }
  accum(selfv);  // self-loop (pre-scaled by dinv[node])

  float xv[8] = {x0.x, x0.y, x0.z, x0.w, x1.x, x1.y, x1.z, x1.w};
  float bv[8] = {b0.x, b0.y, b0.z, b0.w, b1v.x, b1v.y, b1v.z, b1v.w};
  uint outp[4];
#pragma unroll
  for (int i = 0; i < 4; ++i) {
    ushort lo = f2bf(fmaxf(s[2*i]   * dn + bv[2*i],   0.f) + xv[2*i]);
    ushort hi = f2bf(fmaxf(s[2*i+1] * dn + bv[2*i+1], 0.f) + xv[2*i+1]);
    outp[i] = (uint)lo | ((uint)hi << 16);
  }
  *(uint4*)(aggb + (size_t)node * DN + d0) = *(uint4*)outp;
}

// ------------- fused MFMA MLP: out = relu(relu(a@W1+b1)@W2+b2)@W3+b3 ---------

__global__ __launch_bounds__(256, 2) void k_mlp(const ushort* __restrict__ aggb,
                                                const ushort* __restrict__ W1p,
                                                const float* __restrict__ b1,
                                                const ushort* __restrict__ W2p,
                                                const float* __restrict__ b2,
                                                const float* __restrict__ W3,
                                                const float* __restrict__ b3,
                                                float* __restrict__ out, int N) {
  __shared__ ushort aT[64 * 128];   // 16 KB (reused as pf[4][64] floats later)
  __shared__ ushort t1[64 * 512];   // 64 KB
  int t = threadIdx.x;
  int row0 = blockIdx.x * 64;

#pragma unroll
  for (int i = 0; i < 4; ++i) {
    int c = t + 256 * i;
    int r = c >> 4;
    int cb = (c & 15) * 16;
    int gr = row0 + r;
    uint4 v = {0, 0, 0, 0};
    if (gr < N) v = *(const uint4*)(aggb + (size_t)gr * DN + (c & 15) * 8);
    *(uint4*)((char*)aT + r * 256 + (cb ^ ((r & 7) << 4))) = v;
  }
  __syncthreads();

  int w = t >> 6, l = t & 63;
  int lr = l & 15, lk = l >> 4;

  // ---- stage 1: t1[:, w*128:(w+1)*128) = relu(a @ W1 + b1) ----
  const short8_t* pb1 = (const short8_t*)W1p;
  f32x4 acc1[4][8];
#pragma unroll
  for (int mf = 0; mf < 4; ++mf)
#pragma unroll
    for (int n = 0; n < 8; ++n) acc1[mf][n] = (f32x4){0.f,0.f,0.f,0.f};

  auto s1_load = [&](short8_t (&bb)[8], int ks) {
#pragma unroll
    for (int n = 0; n < 8; ++n)
      bb[n] = pb1[((w * 8 + n) * 4 + ks) * 64 + l];
  };
  auto s1_mfma = [&](short8_t (&bb)[8], int ks) {
    short8_t a[4];
#pragma unroll
    for (int mf = 0; mf < 4; ++mf) {
      int r = mf * 16 + lr;
      a[mf] = *(const short8_t*)((const char*)aT + r * 256 + ((ks * 64 + lk * 16) ^ ((r & 7) << 4)));
    }
#pragma unroll
    for (int mf = 0; mf < 4; ++mf)
#pragma unroll
      for (int n = 0; n < 8; ++n)
        acc1[mf][n] = __builtin_amdgcn_mfma_f32_16x16x32_bf16(a[mf], bb[n], acc1[mf][n], 0, 0, 0);
  };

  {
    short8_t bA[8], bB[8];
    s1_load(bA, 0);
    s1_load(bB, 1); s1_mfma(bA, 0);
    s1_load(bA, 2); s1_mfma(bB, 1);
    s1_load(bB, 3); s1_mfma(bA, 2);
    s1_mfma(bB, 3);
  }

#pragma unroll
  for (int n = 0; n < 8; ++n) {
    int col = (w * 8 + n) * 16 + lr;
    float bb = b1[col];
#pragma unroll
    for (int mf = 0; mf < 4; ++mf)
#pragma unroll
      for (int r2 = 0; r2 < 4; ++r2) {
        int rr = mf * 16 + lk * 4 + r2;
        *(ushort*)((char*)t1 + rr * 1024 + ((col * 2) ^ ((rr & 7) << 4))) =
            f2bf(fmaxf(acc1[mf][n][r2] + bb, 0.f));
      }
  }
  __syncthreads();

  // ---- stage 2: c2[:, w*64:(w+1)*64) = t1 @ W2, K=512 ----
  const short8_t* pb2 = (const short8_t*)W2p;
  f32x4 acc2[4][4];
#pragma unroll
  for (int mf = 0; mf < 4; ++mf)
#pragma unroll
    for (int n = 0; n < 4; ++n) acc2[mf][n] = (f32x4){0.f,0.f,0.f,0.f};

  auto s2_load = [&](short8_t (&bb)[8], int p) {
#pragma unroll
    for (int n = 0; n < 4; ++n) {
      bb[n]     = pb2[((w * 4 + n) * 16 + 2 * p)     * 64 + l];
      bb[4 + n] = pb2[((w * 4 + n) * 16 + 2 * p + 1) * 64 + l];
    }
  };
  auto s2_mfma = [&](short8_t (&bb)[8], int p) {
#pragma unroll
    for (int h = 0; h < 2; ++h) {
      int ks = 2 * p + h;
      short8_t a[4];
#pragma unroll
      for (int mf = 0; mf < 4; ++mf) {
        int r = mf * 16 + lr;
        a[mf] = *(const short8_t*)((const char*)t1 + r * 1024 + ((ks * 64 + lk * 16) ^ ((r & 7) << 4)));
      }
#pragma unroll
      for (int mf = 0; mf < 4; ++mf)
#pragma unroll
        for (int n = 0; n < 4; ++n)
          acc2[mf][n] = __builtin_amdgcn_mfma_f32_16x16x32_bf16(a[mf], bb[h * 4 + n], acc2[mf][n], 0, 0, 0);
    }
  };

  {
    short8_t cA[8], cB[8];
    s2_load(cA, 0);
    s2_load(cB, 1); s2_mfma(cA, 0);
    s2_load(cA, 2); s2_mfma(cB, 1);
    s2_load(cB, 3); s2_mfma(cA, 2);
    s2_load(cA, 4); s2_mfma(cB, 3);
    s2_load(cB, 5); s2_mfma(cA, 4);
    s2_load(cA, 6); s2_mfma(cB, 5);
    s2_load(cB, 7); s2_mfma(cA, 6);
    s2_mfma(cB, 7);
  }

  // ---- stage 3 folded: po = relu(c2 + b2) @ W3 (partial over own 64 cols) ----
  float po[4][4];
#pragma unroll
  for (int mf = 0; mf < 4; ++mf)
#pragma unroll
    for (int r2 = 0; r2 < 4; ++r2) po[mf][r2] = 0.f;
#pragma unroll
  for (int n = 0; n < 4; ++n) {
    int col = (w * 4 + n) * 16 + lr;
    float bb = b2[col];
    float w3 = W3[col];
#pragma unroll
    for (int mf = 0; mf < 4; ++mf)
#pragma unroll
      for (int r2 = 0; r2 < 4; ++r2)
        po[mf][r2] += fmaxf(acc2[mf][n][r2] + bb, 0.f) * w3;
  }
#pragma unroll
  for (int mf = 0; mf < 4; ++mf)
#pragma unroll
    for (int r2 = 0; r2 < 4; ++r2) {
      float v = po[mf][r2];
      v += __shfl_xor(v, 1, 64);
      v += __shfl_xor(v, 2, 64);
      v += __shfl_xor(v, 4, 64);
      v += __shfl_xor(v, 8, 64);
      po[mf][r2] = v;
    }
  float* pf = (float*)aT;
  if (lr == 0) {
#pragma unroll
    for (int mf = 0; mf < 4; ++mf)
#pragma unroll
      for (int r2 = 0; r2 < 4; ++r2)
        pf[w * 64 + mf * 16 + lk * 4 + r2] = po[mf][r2];
  }
  __syncthreads();
  if (t < 64) {
    int gr = row0 + t;
    if (gr < N)
      out[gr] = pf[t] + pf[64 + t] + pf[128 + t] + pf[192 + t] + b3[0];
  }
}

// ------------------------------- launcher ------------------------------------

extern "C" void kernel_launch(void* const* d_in, const int* in_sizes, int n_in,
                              void* d_out, int out_size, void* d_ws, size_t ws_size,
                              hipStream_t stream) {
  const float* x  = (const float*)d_in[0];
  const int*   ei = (const int*)d_in[1];
  const float* Wg = (const float*)d_in[2];
  const float* bg = (const float*)d_in[3];
  const float* W1 = (const float*)d_in[4];
  const float* b1 = (const float*)d_in[5];
  const float* W2 = (const float*)d_in[6];
  const float* b2 = (const float*)d_in[7];
  const float* W3 = (const float*)d_in[8];
  const float* b3 = (const float*)d_in[9];
  float* out = (float*)d_out;

  const int N = in_sizes[0] / DN;
  const int E = in_sizes[1] / 2;
  const int NB = (N + 255) >> 8;

  char* ws = (char*)d_ws;
  size_t off = 0;
  auto alloc = [&](size_t bytes) -> void* {
    void* p = ws + off;
    off = (off + bytes + 255) & ~(size_t)255;
    return p;
  };
  int*    deg    = (int*)alloc((size_t)N * 4);
  int*    ro     = (int*)alloc(((size_t)N + 1) * 4);
  int*    sums   = (int*)alloc(4096);
  int*    bcur   = (int*)alloc((size_t)NB * 4);
  float*  dinv   = (float*)alloc((size_t)N * 4);
  int*    csr    = (int*)alloc((size_t)E * 4);
  uint2*  pairs  = (uint2*)alloc((size_t)E * 8);
  ushort* hsb    = (ushort*)alloc((size_t)N * DN * 2);
  ushort* aggb   = (ushort*)alloc((size_t)N * DN * 2);
  ushort* Wgp    = (ushort*)alloc((size_t)DN * DN * 2);
  ushort* W1p    = (ushort*)alloc((size_t)DN * H1N * 2);
  ushort* W2p    = (ushort*)alloc((size_t)H1N * H2N * 2);
  (void)ws_size; (void)n_in; (void)out_size;

  hipMemsetAsync(deg, 0, (size_t)N * 4, stream);

  k_deg<<<(E + 255) / 256, 256, 0, stream>>>(ei + E, deg, E);

  int nb = (N + 255) / 256;
  k_scan_a<<<nb, 256, 0, stream>>>(deg, ro, sums, dinv, N);
  k_scan_b<<<1, 512, 0, stream>>>(sums, nb);
  k_scan_c<<<nb, 256, 0, stream>>>(ro, sums, N, E);

  k_binit<<<(NB + 255) / 256, 256, 0, stream>>>(ro, bcur, N, NB);
  k_bucketA<<<(E + TILE_A - 1) / TILE_A, 256, 0, stream>>>(ei, bcur, pairs, E, NB);
  k_bucketB<<<NB, 256, 0, stream>>>(pairs, ro, csr, N);

  k_pack<<<(DN / 32 * DN / 16 * 64 + 255) / 256, 256, 0, stream>>>(Wg, Wgp, DN, DN);
  k_pack<<<(DN / 32 * H1N / 16 * 64 + 255) / 256, 256, 0, stream>>>(W1, W1p, DN, H1N);
  k_pack<<<(H1N / 32 * H2N / 16 * 64 + 255) / 256, 256, 0, stream>>>(W2, W2p, H1N, H2N);

  int nb64 = (N + 63) / 64;
  k_gemm1<<<nb64, 256, 0, stream>>>(x, Wgp, dinv, hsb, N);
  k_agg<<<(N + 15) / 16, 256, 0, stream>>>(hsb, x, csr, ro, dinv, bg, aggb, N);
  k_mlp<<<nb64, 256, 0, stream>>>(aggb, W1p, b1, W2p, b2, W3, b3, out, N);
}

// Round 6
// 200.615 us; speedup vs baseline: 7.3779x; 1.2911x over previous
//
#include <hip/hip_runtime.h>

#define DN  128
#define H1N 512
#define H2N 256
#define TILE_A 4096
#define BKT_MAX 6144   // bucket capacity: mean 4096, +32 sigma for random graphs

typedef __attribute__((ext_vector_type(8))) short short8_t;   // 8 bf16
typedef __attribute__((ext_vector_type(4))) float f32x4;      // MFMA acc

__device__ inline ushort f2bf(float f) {
  union { float f; unsigned u; } v; v.f = f;
  unsigned r = v.u + 0x7FFF + ((v.u >> 16) & 1);   // RNE
  return (ushort)(r >> 16);
}
__device__ inline float asf(unsigned u) {
  union { unsigned u; float f; } v; v.u = u;
  return v.f;
}

// -------- CSR build, pass 0: per-bucket (dst>>8) counts, LDS histogram -------

__global__ __launch_bounds__(256) void k_bcount(const int* __restrict__ dst,
                                                int* __restrict__ bcnt, int E) {
  __shared__ int h[512];
  int t = threadIdx.x;
  for (int i = t; i < 512; i += 256) h[i] = 0;
  __syncthreads();
  int base = blockIdx.x * TILE_A;
  int cnt = E - base; if (cnt > TILE_A) cnt = TILE_A;
  for (int k = t; k < cnt; k += 256) atomicAdd(&h[dst[base + k] >> 8], 1);
  __syncthreads();
  for (int i = t; i < 512; i += 256)
    if (h[i]) atomicAdd(&bcnt[i], h[i]);
}

// -------- CSR build, pass 0b: scan buckets (1 block) --------

__global__ __launch_bounds__(512) void k_bscan(const int* __restrict__ bcnt,
                                               int* __restrict__ bbase,
                                               int* __restrict__ bcur,
                                               int* __restrict__ ro,
                                               int NB, int N, int E) {
  __shared__ int s[512];
  int t = threadIdx.x;
  int v = (t < NB) ? bcnt[t] : 0;
  s[t] = v; __syncthreads();
  for (int o = 1; o < 512; o <<= 1) {
    int a = (t >= o) ? s[t - o] : 0;
    __syncthreads();
    s[t] += a;
    __syncthreads();
  }
  if (t < NB) { bbase[t] = s[t] - v; bcur[t] = s[t] - v; }
  if (t == 0) { bbase[NB] = E; ro[N] = E; }
}

// -------- CSR build, pass A: tile-reorder bucketize (coalesced writes) -------

__global__ __launch_bounds__(256) void k_bucketA(const int* __restrict__ ei,
                                                 int* __restrict__ bcur,
                                                 uint2* __restrict__ pairs,
                                                 int E, int NB) {
  __shared__ int hist[512];
  __shared__ int start[512];
  __shared__ int cur[512];
  __shared__ int gbase[512];
  __shared__ uint2 lp[TILE_A];   // 32 KB
  int t = threadIdx.x;
  int base = blockIdx.x * TILE_A;
  int cnt = E - base; if (cnt > TILE_A) cnt = TILE_A;

  for (int i = t; i < 512; i += 256) hist[i] = 0;
  __syncthreads();

  int sreg[16], dreg[16];
#pragma unroll
  for (int k = 0; k < 16; ++k) {
    int idx = t + 256 * k;
    bool v = idx < cnt;
    sreg[k] = v ? ei[base + idx] : 0;
    dreg[k] = v ? ei[E + base + idx] : -1;
    if (v) atomicAdd(&hist[dreg[k] >> 8], 1);
  }
  __syncthreads();

  for (int i = t; i < 512; i += 256) start[i] = hist[i];
  __syncthreads();
  for (int o = 1; o < 512; o <<= 1) {
    int i0 = t, i1 = t + 256;
    int v0 = (i0 >= o) ? start[i0 - o] : 0;
    int v1 = (i1 >= o) ? start[i1 - o] : 0;
    __syncthreads();
    start[i0] += v0;
    start[i1] += v1;
    __syncthreads();
  }
  for (int i = t; i < 512; i += 256) start[i] -= hist[i];  // exclusive
  __syncthreads();
  for (int i = t; i < 512; i += 256) cur[i] = start[i];
  __syncthreads();

#pragma unroll
  for (int k = 0; k < 16; ++k) {
    if (dreg[k] >= 0) {
      int d = dreg[k] >> 8;
      int p = atomicAdd(&cur[d], 1);
      lp[p] = make_uint2((unsigned)sreg[k], (unsigned)dreg[k]);
    }
  }
  __syncthreads();

  for (int i = t; i < NB; i += 256)
    gbase[i] = hist[i] ? atomicAdd(&bcur[i], hist[i]) : 0;
  __syncthreads();

  for (int p = t; p < cnt; p += 256) {
    uint2 pr = lp[p];
    int d = (int)(pr.y >> 8);
    pairs[gbase[d] + (p - start[d])] = pr;
  }
}

// ----- CSR build, pass B: per-bucket node sort; emits csr + ro + dinv --------

__global__ __launch_bounds__(256) void k_bucketB(const uint2* __restrict__ pairs,
                                                 const int* __restrict__ bbase,
                                                 int* __restrict__ csr,
                                                 int* __restrict__ ro,
                                                 float* __restrict__ dinv,
                                                 int N) {
  __shared__ int hist[256];
  __shared__ int cur[256];
  __shared__ int lout[BKT_MAX];    // 24 KB
  __shared__ uint2 lp[BKT_MAX];    // 48 KB
  int b = blockIdx.x, t = threadIdx.x;
  int p0 = bbase[b];
  int cnt = bbase[b + 1] - p0;

  hist[t] = 0;
  __syncthreads();
  for (int k = t; k < cnt; k += 256) {
    uint2 pr = pairs[p0 + k];
    if (k < BKT_MAX) lp[k] = pr;
    atomicAdd(&hist[pr.y & 255u], 1);
  }
  __syncthreads();

  int v = hist[t];
  cur[t] = v; __syncthreads();
  for (int o = 1; o < 256; o <<= 1) {
    int a = (t >= o) ? cur[t - o] : 0;
    __syncthreads();
    cur[t] += a;
    __syncthreads();
  }
  int excl = cur[t] - v;
  int node = (b << 8) + t;
  if (node < N) {
    ro[node] = p0 + excl;
    dinv[node] = rsqrtf((float)(v + 1));  // +1 self-loop
  }
  __syncthreads();
  cur[t] = excl;
  __syncthreads();

  for (int k = t; k < cnt; k += 256) {
    uint2 pr = (k < BKT_MAX) ? lp[k] : pairs[p0 + k];
    int p = atomicAdd(&cur[(int)(pr.y & 255u)], 1);
    if (p < BKT_MAX) lout[p] = (int)pr.x;
    else csr[p0 + p] = (int)pr.x;       // overflow slow path (never in practice)
  }
  __syncthreads();
  int lim = cnt < BKT_MAX ? cnt : BKT_MAX;
  for (int k = t; k < lim; k += 256) csr[p0 + k] = lout[k];
}

// ------------- weight repack into MFMA B-fragment order (bf16), fused --------
// Wp[ct][ks][lane][8] = W[ks*32 + (lane>>4)*8 + r][ct*16 + (lane&15)]

__device__ inline void pack_one(int idx, const float* __restrict__ W,
                                ushort* __restrict__ Wp, int K, int Ncols) {
  int ksn = K >> 5;
  int l  = idx & 63;
  int ks = (idx >> 6) % ksn;
  int ct = idx / (64 * ksn);
  int col = ct * 16 + (l & 15);
  int kb  = ks * 32 + (l >> 4) * 8;
  short8_t v;
#pragma unroll
  for (int r = 0; r < 8; ++r)
    v[r] = (short)f2bf(W[(size_t)(kb + r) * Ncols + col]);
  *(short8_t*)&Wp[(size_t)idx * 8] = v;
}

__global__ __launch_bounds__(256) void k_packall(const float* __restrict__ Wg,
                                                 const float* __restrict__ W1,
                                                 const float* __restrict__ W2,
                                                 ushort* __restrict__ Wgp,
                                                 ushort* __restrict__ W1p,
                                                 ushort* __restrict__ W2p) {
  int idx = blockIdx.x * 256 + threadIdx.x;
  if (idx < 2048)        pack_one(idx, Wg, Wgp, DN, DN);            // 4*8*64
  else if (idx < 10240)  pack_one(idx - 2048, W1, W1p, DN, H1N);    // 4*32*64
  else if (idx < 26624)  pack_one(idx - 10240, W2, W2p, H1N, H2N);  // 16*16*64
}

// ---------------- GEMM1: hs = (x @ W_gcn) * dinv[row]  (bf16 out) ------------

__global__ __launch_bounds__(256, 4) void k_gemm1(const float* __restrict__ x,
                                                  const ushort* __restrict__ Wgp,
                                                  const float* __restrict__ dinv,
                                                  ushort* __restrict__ hs, int N) {
  __shared__ ushort xT[64 * 128];  // bf16, XOR-swizzled, 16 KB
  int t = threadIdx.x;
  int row0 = blockIdx.x * 64;

#pragma unroll
  for (int i = 0; i < 4; ++i) {
    int c = t + 256 * i;
    int r = c >> 4, d0 = (c & 15) * 8;
    int gr = row0 + r;
    float4 v0 = {0,0,0,0}, v1 = {0,0,0,0};
    if (gr < N) {
      v0 = *(const float4*)(x + (size_t)gr * DN + d0);
      v1 = *(const float4*)(x + (size_t)gr * DN + d0 + 4);
    }
    short8_t p;
    p[0]=(short)f2bf(v0.x); p[1]=(short)f2bf(v0.y); p[2]=(short)f2bf(v0.z); p[3]=(short)f2bf(v0.w);
    p[4]=(short)f2bf(v1.x); p[5]=(short)f2bf(v1.y); p[6]=(short)f2bf(v1.z); p[7]=(short)f2bf(v1.w);
    *(short8_t*)((char*)xT + r * 256 + ((d0 * 2) ^ ((r & 7) << 4))) = p;
  }
  __syncthreads();

  int w = t >> 6, l = t & 63;
  int lr = l & 15, lk = l >> 4;
  const short8_t* pbg = (const short8_t*)Wgp;

  f32x4 acc[4][2];
#pragma unroll
  for (int mf = 0; mf < 4; ++mf)
#pragma unroll
    for (int n = 0; n < 2; ++n) acc[mf][n] = (f32x4){0.f,0.f,0.f,0.f};

  auto g_load = [&](short8_t (&bb)[2], int ks) {
#pragma unroll
    for (int n = 0; n < 2; ++n)
      bb[n] = pbg[((w * 2 + n) * 4 + ks) * 64 + l];
  };
  auto g_mfma = [&](short8_t (&bb)[2], int ks) {
    short8_t a[4];
#pragma unroll
    for (int mf = 0; mf < 4; ++mf) {
      int r = mf * 16 + lr;
      a[mf] = *(const short8_t*)((const char*)xT + r * 256 + ((ks * 64 + lk * 16) ^ ((r & 7) << 4)));
    }
#pragma unroll
    for (int mf = 0; mf < 4; ++mf)
#pragma unroll
      for (int n = 0; n < 2; ++n)
        acc[mf][n] = __builtin_amdgcn_mfma_f32_16x16x32_bf16(a[mf], bb[n], acc[mf][n], 0, 0, 0);
  };

  short8_t bA[2], bB[2];
  g_load(bA, 0);
  g_load(bB, 1); g_mfma(bA, 0);
  g_load(bA, 2); g_mfma(bB, 1);
  g_load(bB, 3); g_mfma(bA, 2);
  g_mfma(bB, 3);

  float dv[4][4];
#pragma unroll
  for (int mf = 0; mf < 4; ++mf)
#pragma unroll
    for (int r2 = 0; r2 < 4; ++r2) {
      int gr = row0 + mf * 16 + lk * 4 + r2;
      dv[mf][r2] = (gr < N) ? dinv[gr] : 0.f;
    }
#pragma unroll
  for (int n = 0; n < 2; ++n) {
    int col = (w * 2 + n) * 16 + lr;
#pragma unroll
    for (int mf = 0; mf < 4; ++mf)
#pragma unroll
      for (int r2 = 0; r2 < 4; ++r2) {
        int gr = row0 + mf * 16 + lk * 4 + r2;
        if (gr < N) hs[(size_t)gr * DN + col] = f2bf(acc[mf][n][r2] * dv[mf][r2]);
      }
  }
}

// --------- aggregation: agg = bf16(relu(dinv*(sum+self) + b) + x) ------------

__global__ __launch_bounds__(256) void k_agg(const ushort* __restrict__ hs,
                                             const float* __restrict__ x,
                                             const int* __restrict__ csr,
                                             const int* __restrict__ ro,
                                             const float* __restrict__ dinv,
                                             const float* __restrict__ bg,
                                             ushort* __restrict__ aggb, int N) {
  int t = threadIdx.x;
  int node = blockIdx.x * 16 + (t >> 4);
  if (node >= N) return;
  int d0 = (t & 15) * 8;

  int beg = ro[node], end = ro[node + 1];
  float dn = dinv[node];
  uint4 selfv = *(const uint4*)(hs + (size_t)node * DN + d0);
  float4 x0 = *(const float4*)(x + (size_t)node * DN + d0);
  float4 x1 = *(const float4*)(x + (size_t)node * DN + d0 + 4);
  float4 b0 = *(const float4*)(bg + d0);
  float4 b1v = *(const float4*)(bg + d0 + 4);

  float s[8];
#pragma unroll
  for (int i = 0; i < 8; ++i) s[i] = 0.f;

  auto accum = [&](uint4 v) {
    s[0] += asf(v.x << 16); s[1] += asf(v.x & 0xffff0000u);
    s[2] += asf(v.y << 16); s[3] += asf(v.y & 0xffff0000u);
    s[4] += asf(v.z << 16); s[5] += asf(v.z & 0xffff0000u);
    s[6] += asf(v.w << 16); s[7] += asf(v.w & 0xffff0000u);
  };

  int e = beg;
  for (; e + 4 <= end; e += 4) {
    int i0 = csr[e], i1 = csr[e + 1], i2 = csr[e + 2], i3 = csr[e + 3];
    uint4 v0 = *(const uint4*)(hs + (size_t)i0 * DN + d0);
    uint4 v1 = *(const uint4*)(hs + (size_t)i1 * DN + d0);
    uint4 v2 = *(const uint4*)(hs + (size_t)i2 * DN + d0);
    uint4 v3 = *(const uint4*)(hs + (size_t)i3 * DN + d0);
    accum(v0); accum(v1); accum(v2); accum(v3);
  }
  if (e + 2 <= end) {
    int i0 = csr[e], i1 = csr[e + 1];
    uint4 v0 = *(const uint4*)(hs + (size_t)i0 * DN + d0);
    uint4 v1 = *(const uint4*)(hs + (size_t)i1 * DN + d0);
    accum(v0); accum(v1);
    e += 2;
  }
  if (e < end) {
    int i0 = csr[e];
    accum(*(const uint4*)(hs + (size_t)i0 * DN + d0));
  }
  accum(selfv);  // self-loop (pre-scaled by dinv[node])

  float xv[8] = {x0.x, x0.y, x0.z, x0.w, x1.x, x1.y, x1.z, x1.w};
  float bv[8] = {b0.x, b0.y, b0.z, b0.w, b1v.x, b1v.y, b1v.z, b1v.w};
  uint outp[4];
#pragma unroll
  for (int i = 0; i < 4; ++i) {
    ushort lo = f2bf(fmaxf(s[2*i]   * dn + bv[2*i],   0.f) + xv[2*i]);
    ushort hi = f2bf(fmaxf(s[2*i+1] * dn + bv[2*i+1], 0.f) + xv[2*i+1]);
    outp[i] = (uint)lo | ((uint)hi << 16);
  }
  *(uint4*)(aggb + (size_t)node * DN + d0) = *(uint4*)outp;
}

// ------------- fused MFMA MLP: out = relu(relu(a@W1+b1)@W2+b2)@W3+b3 ---------
// 64 rows/block, 4 waves, col-split, stage-2 B prefetch 2-deep.

__global__ __launch_bounds__(256, 2) void k_mlp(const ushort* __restrict__ aggb,
                                                const ushort* __restrict__ W1p,
                                                const float* __restrict__ b1,
                                                const ushort* __restrict__ W2p,
                                                const float* __restrict__ b2,
                                                const float* __restrict__ W3,
                                                const float* __restrict__ b3,
                                                float* __restrict__ out, int N) {
  __shared__ ushort aT[64 * 128];   // 16 KB (reused as pf[4][64] floats later)
  __shared__ ushort t1[64 * 512];   // 64 KB
  int t = threadIdx.x;
  int row0 = blockIdx.x * 64;

#pragma unroll
  for (int i = 0; i < 4; ++i) {
    int c = t + 256 * i;
    int r = c >> 4;
    int cb = (c & 15) * 16;
    int gr = row0 + r;
    uint4 v = {0, 0, 0, 0};
    if (gr < N) v = *(const uint4*)(aggb + (size_t)gr * DN + (c & 15) * 8);
    *(uint4*)((char*)aT + r * 256 + (cb ^ ((r & 7) << 4))) = v;
  }
  __syncthreads();

  int w = t >> 6, l = t & 63;
  int lr = l & 15, lk = l >> 4;

  // ---- stage 1: t1[:, w*128:(w+1)*128) = relu(a @ W1 + b1) ----
  const short8_t* pb1 = (const short8_t*)W1p;
  f32x4 acc1[4][8];
#pragma unroll
  for (int mf = 0; mf < 4; ++mf)
#pragma unroll
    for (int n = 0; n < 8; ++n) acc1[mf][n] = (f32x4){0.f,0.f,0.f,0.f};

  auto s1_load = [&](short8_t (&bb)[8], int ks) {
#pragma unroll
    for (int n = 0; n < 8; ++n)
      bb[n] = pb1[((w * 8 + n) * 4 + ks) * 64 + l];
  };
  auto s1_mfma = [&](short8_t (&bb)[8], int ks) {
    short8_t a[4];
#pragma unroll
    for (int mf = 0; mf < 4; ++mf) {
      int r = mf * 16 + lr;
      a[mf] = *(const short8_t*)((const char*)aT + r * 256 + ((ks * 64 + lk * 16) ^ ((r & 7) << 4)));
    }
#pragma unroll
    for (int mf = 0; mf < 4; ++mf)
#pragma unroll
      for (int n = 0; n < 8; ++n)
        acc1[mf][n] = __builtin_amdgcn_mfma_f32_16x16x32_bf16(a[mf], bb[n], acc1[mf][n], 0, 0, 0);
  };

  {
    short8_t bA[8], bB[8];
    s1_load(bA, 0);
    s1_load(bB, 1); s1_mfma(bA, 0);
    s1_load(bA, 2); s1_mfma(bB, 1);
    s1_load(bB, 3); s1_mfma(bA, 2);
    s1_mfma(bB, 3);
  }

#pragma unroll
  for (int n = 0; n < 8; ++n) {
    int col = (w * 8 + n) * 16 + lr;
    float bb = b1[col];
#pragma unroll
    for (int mf = 0; mf < 4; ++mf)
#pragma unroll
      for (int r2 = 0; r2 < 4; ++r2) {
        int rr = mf * 16 + lk * 4 + r2;
        *(ushort*)((char*)t1 + rr * 1024 + ((col * 2) ^ ((rr & 7) << 4))) =
            f2bf(fmaxf(acc1[mf][n][r2] + bb, 0.f));
      }
  }
  __syncthreads();

  // ---- stage 2: c2[:, w*64:(w+1)*64) = t1 @ W2, K=512, 2-deep prefetch ----
  const short8_t* pb2 = (const short8_t*)W2p;
  f32x4 acc2[4][4];
#pragma unroll
  for (int mf = 0; mf < 4; ++mf)
#pragma unroll
    for (int n = 0; n < 4; ++n) acc2[mf][n] = (f32x4){0.f,0.f,0.f,0.f};

  auto s2_load = [&](short8_t (&bb)[8], int p) {
#pragma unroll
    for (int n = 0; n < 4; ++n) {
      bb[n]     = pb2[((w * 4 + n) * 16 + 2 * p)     * 64 + l];
      bb[4 + n] = pb2[((w * 4 + n) * 16 + 2 * p + 1) * 64 + l];
    }
  };
  auto s2_mfma = [&](short8_t (&bb)[8], int p) {
#pragma unroll
    for (int h = 0; h < 2; ++h) {
      int ks = 2 * p + h;
      short8_t a[4];
#pragma unroll
      for (int mf = 0; mf < 4; ++mf) {
        int r = mf * 16 + lr;
        a[mf] = *(const short8_t*)((const char*)t1 + r * 1024 + ((ks * 64 + lk * 16) ^ ((r & 7) << 4)));
      }
#pragma unroll
      for (int mf = 0; mf < 4; ++mf)
#pragma unroll
        for (int n = 0; n < 4; ++n)
          acc2[mf][n] = __builtin_amdgcn_mfma_f32_16x16x32_bf16(a[mf], bb[h * 4 + n], acc2[mf][n], 0, 0, 0);
    }
  };

  {
    short8_t c0[8], c1[8], c2[8];
    s2_load(c0, 0); s2_load(c1, 1);
    s2_load(c2, 2); s2_mfma(c0, 0);
    s2_load(c0, 3); s2_mfma(c1, 1);
    s2_load(c1, 4); s2_mfma(c2, 2);
    s2_load(c2, 5); s2_mfma(c0, 3);
    s2_load(c0, 6); s2_mfma(c1, 4);
    s2_load(c1, 7); s2_mfma(c2, 5);
    s2_mfma(c0, 6);
    s2_mfma(c1, 7);
  }

  // ---- stage 3 folded: po = relu(c2 + b2) @ W3 (partial over own 64 cols) ----
  float po[4][4];
#pragma unroll
  for (int mf = 0; mf < 4; ++mf)
#pragma unroll
    for (int r2 = 0; r2 < 4; ++r2) po[mf][r2] = 0.f;
#pragma unroll
  for (int n = 0; n < 4; ++n) {
    int col = (w * 4 + n) * 16 + lr;
    float bb = b2[col];
    float w3 = W3[col];
#pragma unroll
    for (int mf = 0; mf < 4; ++mf)
#pragma unroll
      for (int r2 = 0; r2 < 4; ++r2)
        po[mf][r2] += fmaxf(acc2[mf][n][r2] + bb, 0.f) * w3;
  }
#pragma unroll
  for (int mf = 0; mf < 4; ++mf)
#pragma unroll
    for (int r2 = 0; r2 < 4; ++r2) {
      float v = po[mf][r2];
      v += __shfl_xor(v, 1, 64);
      v += __shfl_xor(v, 2, 64);
      v += __shfl_xor(v, 4, 64);
      v += __shfl_xor(v, 8, 64);
      po[mf][r2] = v;
    }
  float* pf = (float*)aT;
  if (lr == 0) {
#pragma unroll
    for (int mf = 0; mf < 4; ++mf)
#pragma unroll
      for (int r2 = 0; r2 < 4; ++r2)
        pf[w * 64 + mf * 16 + lk * 4 + r2] = po[mf][r2];
  }
  __syncthreads();
  if (t < 64) {
    int gr = row0 + t;
    if (gr < N)
      out[gr] = pf[t] + pf[64 + t] + pf[128 + t] + pf[192 + t] + b3[0];
  }
}

// ------------------------------- launcher ------------------------------------

extern "C" void kernel_launch(void* const* d_in, const int* in_sizes, int n_in,
                              void* d_out, int out_size, void* d_ws, size_t ws_size,
                              hipStream_t stream) {
  const float* x  = (const float*)d_in[0];
  const int*   ei = (const int*)d_in[1];
  const float* Wg = (const float*)d_in[2];
  const float* bg = (const float*)d_in[3];
  const float* W1 = (const float*)d_in[4];
  const float* b1 = (const float*)d_in[5];
  const float* W2 = (const float*)d_in[6];
  const float* b2 = (const float*)d_in[7];
  const float* W3 = (const float*)d_in[8];
  const float* b3 = (const float*)d_in[9];
  float* out = (float*)d_out;

  const int N = in_sizes[0] / DN;
  const int E = in_sizes[1] / 2;
  const int NB = (N + 255) >> 8;

  char* ws = (char*)d_ws;
  size_t off = 0;
  auto alloc = [&](size_t bytes) -> void* {
    void* p = ws + off;
    off = (off + bytes + 255) & ~(size_t)255;
    return p;
  };
  int*    bcnt   = (int*)alloc((size_t)NB * 4);
  int*    bbase  = (int*)alloc(((size_t)NB + 1) * 4);
  int*    bcur   = (int*)alloc((size_t)NB * 4);
  int*    ro     = (int*)alloc(((size_t)N + 1) * 4);
  float*  dinv   = (float*)alloc((size_t)N * 4);
  int*    csr    = (int*)alloc((size_t)E * 4);
  uint2*  pairs  = (uint2*)alloc((size_t)E * 8);
  ushort* hsb    = (ushort*)alloc((size_t)N * DN * 2);
  ushort* aggb   = (ushort*)alloc((size_t)N * DN * 2);
  ushort* Wgp    = (ushort*)alloc((size_t)DN * DN * 2);
  ushort* W1p    = (ushort*)alloc((size_t)DN * H1N * 2);
  ushort* W2p    = (ushort*)alloc((size_t)H1N * H2N * 2);
  (void)ws_size; (void)n_in; (void)out_size;

  hipMemsetAsync(bcnt, 0, (size_t)NB * 4, stream);

  int nTiles = (E + TILE_A - 1) / TILE_A;
  k_bcount<<<nTiles, 256, 0, stream>>>(ei + E, bcnt, E);
  k_bscan<<<1, 512, 0, stream>>>(bcnt, bbase, bcur, ro, NB, N, E);
  k_bucketA<<<nTiles, 256, 0, stream>>>(ei, bcur, pairs, E, NB);
  k_bucketB<<<NB, 256, 0, stream>>>(pairs, bbase, csr, ro, dinv, N);

  k_packall<<<104, 256, 0, stream>>>(Wg, W1, W2, Wgp, W1p, W2p);

  int nb64 = (N + 63) / 64;
  k_gemm1<<<nb64, 256, 0, stream>>>(x, Wgp, dinv, hsb, N);
  k_agg<<<(N + 15) / 16, 256, 0, stream>>>(hsb, x, csr, ro, dinv, bg, aggb, N);
  k_mlp<<<nb64, 256, 0, stream>>>(aggb, W1p, b1, W2p, b2, W3, b3, out, N);
}